// Round 1
// 318.654 us; speedup vs baseline: 1.0569x; 1.0569x over previous
//
#include <hip/hip_runtime.h>
#include <hip/hip_bf16.h>
#include <stdint.h>

// MHA: B=4, S=2048, D_MODEL=1024, H=16, hd=64.
// Interface: fp32 in / fp32 out. Internal compute: bf16 MFMA.

#define B_  4
#define S_  2048
#define DM  1024
#define H_  16
#define HD  64
#define BH  (B_ * H_)

typedef __attribute__((ext_vector_type(8))) short short8;
typedef __attribute__((ext_vector_type(4))) float f32x4;

union U8 { short8 v; ushort u[8]; };

__device__ __forceinline__ ushort f2bf(float f) {
  union { float f; uint32_t i; } x; x.f = f;
  uint32_t r = (x.i + 0x7FFFu + ((x.i >> 16) & 1u)) >> 16;
  return (ushort)r;
}

// packed f32x2 -> bf16x2 (RNE), gfx950 hw convert; no builtin exists (m240)
__device__ __forceinline__ uint32_t cvt_pk_bf16(float a, float b) {
  uint32_t r;
  asm("v_cvt_pk_bf16_f32 %0, %1, %2" : "=v"(r) : "v"(a), "v"(b));
  return r;
}

// raw 2^x (v_exp_f32 IS exp2)
__device__ __forceinline__ float exp2f_fast(float x) {
  float r;
  asm("v_exp_f32 %0, %1" : "=v"(r) : "v"(x));
  return r;
}

__device__ __forceinline__ void glds16(const ushort* g, ushort* l) {
  __builtin_amdgcn_global_load_lds(
      (const __attribute__((address_space(1))) void*)g,
      (__attribute__((address_space(3))) void*)l, 16, 0, 0);
}

// ---------------- weight ingest: fp32 [1024][1024] -> bf16 transposed ----------------
__global__ __launch_bounds__(256) void transposeW(const float* __restrict__ src,
                                                  ushort* __restrict__ dst) {
  __shared__ __align__(16) ushort tile[64][72];
  const int t = threadIdx.x;
  const int bx = blockIdx.x & 15;   // src col block
  const int by = blockIdx.x >> 4;   // src row block
#pragma unroll
  for (int i = 0; i < 2; i++) {
    int e = (i * 256 + t) * 8;
    int r = e >> 6, c = e & 63;
    const float* sp = src + (size_t)(by * 64 + r) * 1024 + bx * 64 + c;
    float4 a = ((const float4*)sp)[0];
    float4 b = ((const float4*)sp)[1];
    tile[r][c + 0] = f2bf(a.x); tile[r][c + 1] = f2bf(a.y);
    tile[r][c + 2] = f2bf(a.z); tile[r][c + 3] = f2bf(a.w);
    tile[r][c + 4] = f2bf(b.x); tile[r][c + 5] = f2bf(b.y);
    tile[r][c + 6] = f2bf(b.z); tile[r][c + 7] = f2bf(b.w);
  }
  __syncthreads();
#pragma unroll
  for (int i = 0; i < 2; i++) {
    int e = (i * 256 + t) * 8;
    int r = e >> 6, c = e & 63;
    U8 st;
#pragma unroll
    for (int j = 0; j < 8; j++) st.u[j] = tile[c + j][r];
    *(short8*)(dst + (size_t)(bx * 64 + r) * 1024 + by * 64 + c) = st.v;
  }
}

// ---------------- per-head V transpose: bf16 [BH][S][64] -> [BH][64][S] ----------------
__global__ __launch_bounds__(256) void transpose_v_k(const ushort* __restrict__ v,
                                                     ushort* __restrict__ vt) {
  __shared__ __align__(16) ushort tile[64][72];
  const int t = threadIdx.x;
  const int bh = blockIdx.x >> 5;
  const int s0 = (blockIdx.x & 31) * 64;
  const ushort* src = v + (size_t)bh * S_ * HD;
  ushort* dst = vt + (size_t)bh * HD * S_;
#pragma unroll
  for (int i = 0; i < 2; i++) {
    int e = (i * 256 + t) * 8;
    int r = e >> 6, c = e & 63;            // r: s-local, c: d
    U8 ld;
    ld.v = *(const short8*)(src + (size_t)(s0 + r) * HD + c);
#pragma unroll
    for (int j = 0; j < 8; j++) tile[r][c + j] = ld.u[j];
  }
  __syncthreads();
#pragma unroll
  for (int i = 0; i < 2; i++) {
    int e = (i * 256 + t) * 8;
    int r = e >> 6, c = e & 63;            // r: d, c: s-local
    U8 st;
#pragma unroll
    for (int j = 0; j < 8; j++) st.u[j] = tile[c + j][r];
    *(short8*)(dst + (size_t)r * S_ + s0 + c) = st.v;
  }
}

// ---------------- GEMM: C[M][N] = A[M][K] * BT[N][K]^T + bias ----------------
// AFP32: A is fp32 (reg-staged + cvt), else bf16 via global_load_lds.
// CMODE 0: fp32 row-major out. CMODE 1: bf16 head-split [B][H][S][64] out.
template<int AFP32, int CMODE>
__global__ __launch_bounds__(256, 2) void gemm_bt(
    const void* __restrict__ Ap, const ushort* __restrict__ BT,
    const float* __restrict__ bias, void* __restrict__ Cp,
    int M, int N, int K, float oscale) {
  __shared__ __align__(16) ushort lA[128 * 32];
  __shared__ __align__(16) ushort lB[128 * 32];
  const int t = threadIdx.x;
  const int lane = t & 63;
  const int w = t >> 6;
  const int wr = w >> 1, wc = w & 1;
  const int bm0 = blockIdx.x * 128;
  const int bn0 = blockIdx.y * 128;
  f32x4 acc[4][4] = {};

  const int arow = t >> 2;           // 0..63
  const int acol = (t & 3) * 8;      // element offset within 32-wide K slab
  const ushort* gA0 = (const ushort*)Ap + (size_t)(bm0 + arow) * K + acol;
  const ushort* gA1 = (const ushort*)Ap + (size_t)(bm0 + 64 + arow) * K + acol;
  const float*  fA0 = (const float*)Ap + (size_t)(bm0 + arow) * K + acol;
  const float*  fA1 = (const float*)Ap + (size_t)(bm0 + 64 + arow) * K + acol;
  const ushort* gB0 = BT + (size_t)(bn0 + arow) * K + acol;
  const ushort* gB1 = BT + (size_t)(bn0 + 64 + arow) * K + acol;

  for (int k0 = 0; k0 < K; k0 += 32) {
    if (k0) __syncthreads();
    if constexpr (AFP32) {
      float4 x0 = ((const float4*)(fA0 + k0))[0];
      float4 x1 = ((const float4*)(fA0 + k0))[1];
      float4 y0 = ((const float4*)(fA1 + k0))[0];
      float4 y1 = ((const float4*)(fA1 + k0))[1];
      U8 s0, s1;
      s0.u[0] = f2bf(x0.x); s0.u[1] = f2bf(x0.y); s0.u[2] = f2bf(x0.z); s0.u[3] = f2bf(x0.w);
      s0.u[4] = f2bf(x1.x); s0.u[5] = f2bf(x1.y); s0.u[6] = f2bf(x1.z); s0.u[7] = f2bf(x1.w);
      s1.u[0] = f2bf(y0.x); s1.u[1] = f2bf(y0.y); s1.u[2] = f2bf(y0.z); s1.u[3] = f2bf(y0.w);
      s1.u[4] = f2bf(y1.x); s1.u[5] = f2bf(y1.y); s1.u[6] = f2bf(y1.z); s1.u[7] = f2bf(y1.w);
      *(short8*)&lA[t * 8] = s0.v;
      *(short8*)&lA[2048 + t * 8] = s1.v;
    } else {
      glds16(gA0 + k0, &lA[t * 8]);
      glds16(gA1 + k0, &lA[2048 + t * 8]);
    }
    glds16(gB0 + k0, &lB[t * 8]);
    glds16(gB1 + k0, &lB[2048 + t * 8]);
    __syncthreads();
    short8 af[4], bf[4];
#pragma unroll
    for (int i = 0; i < 4; i++)
      af[i] = *(const short8*)&lA[(wr * 64 + i * 16 + (lane & 15)) * 32 + (lane >> 4) * 8];
#pragma unroll
    for (int j = 0; j < 4; j++)
      bf[j] = *(const short8*)&lB[(wc * 64 + j * 16 + (lane & 15)) * 32 + (lane >> 4) * 8];
#pragma unroll
    for (int i = 0; i < 4; i++)
#pragma unroll
      for (int j = 0; j < 4; j++)
        acc[i][j] = __builtin_amdgcn_mfma_f32_16x16x32_bf16(af[i], bf[j], acc[i][j], 0, 0, 0);
  }

  const int r0 = (lane >> 4) * 4;
#pragma unroll
  for (int j = 0; j < 4; j++) {
    const int col = bn0 + wc * 64 + j * 16 + (lane & 15);
    const float bc = bias[col];
#pragma unroll
    for (int i = 0; i < 4; i++) {
      const int row = bm0 + wr * 64 + i * 16 + r0;
#pragma unroll
      for (int r = 0; r < 4; r++) {
        float val = (acc[i][j][r] + bc) * oscale;
        if constexpr (CMODE == 0) {
          ((float*)Cp)[(size_t)(row + r) * N + col] = val;
        } else {
          int rr = row + r;
          int b = rr >> 11, s = rr & 2047;
          int h = col >> 6, d = col & 63;
          ((ushort*)Cp)[(((size_t)b * H_ + h) * S_ + s) * HD + d] = f2bf(val);
        }
      }
    }
  }
}

// ---------------- flash attention (LDS-staged, 2-phase pipelined) ----------------
// q,k: bf16 [BH][S][64] (q pre-scaled by log2(e)/8 -> scores in log2 domain),
// vt: bf16 [BH][64][S], o: bf16 [B][S][1024]
// Block: 256 threads (4 waves), Q-tile 128 rows (32/wave). KV tile 64.
// l tracked via MFMA with a ones B-fragment. P = exp2(s' - m') via raw v_exp_f32.
// Defer-max: skip rescale while tile max grows <= 8*log2e (P bounded by e^8).
// LDS = 16K(kbuf)+16K(vbuf)+8K(pbuf) = 40960 B exactly -> 4 blocks/CU (full grid resident).
__global__ __launch_bounds__(256, 4) void attn(
    const ushort* __restrict__ q, const ushort* __restrict__ k,
    const ushort* __restrict__ vt, ushort* __restrict__ o) {
  __shared__ __align__(16) ushort kbuf[2][4096];
  __shared__ __align__(16) ushort vbuf[2][4096];
  __shared__ __align__(16) ushort pbuf[4][16][64];  // 16B-chunk XOR-swizzled: phys = chunk ^ (row&7)
  const int t = threadIdx.x;
  const int lane = t & 63;
  const int w = t >> 6;
  // XCD-bijective swizzle: 1024 blocks, 16 q-tiles/head -> one head's blocks share an XCD L2
  const int L = ((blockIdx.x & 7) << 7) + (blockIdx.x >> 3);
  const int bh = L >> 4;
  const int q0 = (L & 15) * 128;
  const int b = bh >> 4, h = bh & 15;
  const int l15 = lane & 15;
  const int prow = (lane >> 4) * 4;

  const ushort* kbase  = k  + (size_t)bh * S_ * HD;
  const ushort* vtbase = vt + (size_t)bh * HD * S_;

  // Q fragments: 32 rows per wave, hd=64 in two K-slabs
  short8 qf[2][2];
#pragma unroll
  for (int qi = 0; qi < 2; qi++) {
    const ushort* qp = q + ((size_t)bh * S_ + q0 + w * 32 + qi * 16 + l15) * HD + (lane >> 4) * 8;
    qf[qi][0] = *(const short8*)qp;
    qf[qi][1] = *(const short8*)(qp + 32);
  }

  // ones B-fragment for l accumulation (bf16 1.0 = 0x3F80)
  short8 onesf;
#pragma unroll
  for (int j = 0; j < 8; j++) onesf[j] = (short)0x3F80;

  // hoisted (loop-invariant) swizzled pbuf addresses: writes [r][cb], reads [ks]
  ushort* pw[4][4];
  const ushort* pr[2];
#pragma unroll
  for (int r = 0; r < 4; r++) {
    const int row = prow + r;
#pragma unroll
    for (int cb = 0; cb < 4; cb++) {
      const int c2 = cb * 2 + (l15 >> 3);
      pw[r][cb] = &pbuf[w][row][((c2 ^ (row & 7)) << 3) + (l15 & 7)];
    }
  }
#pragma unroll
  for (int ks = 0; ks < 2; ks++)
    pr[ks] = &pbuf[w][l15][((ks * 4 + (lane >> 4)) ^ (l15 & 7)) << 3];

  float m_r[2][4];
  f32x4 l_acc[2];
  f32x4 o_acc[2][4];
#pragma unroll
  for (int qi = 0; qi < 2; qi++) {
#pragma unroll
    for (int r = 0; r < 4; r++) m_r[qi][r] = -1e30f;
    l_acc[qi] = (f32x4){0.f, 0.f, 0.f, 0.f};
#pragma unroll
    for (int cb = 0; cb < 4; cb++) o_acc[qi][cb] = (f32x4){0.f, 0.f, 0.f, 0.f};
  }

  // stage one 64-kv tile (K 64x64 row-major, Vt 64x64 row-major) with XOR-swizzled source
  auto STAGE = [&](int sel, int kv0) {
#pragma unroll
    for (int i = 0; i < 2; i++) {
      int c = i * 256 + t;            // 16B-chunk index, 512 chunks per tile
      int row = c >> 3;
      int cc = (c & 7) ^ (row & 7);   // pre-swizzled source chunk
      glds16(kbase + (size_t)(kv0 + row) * HD + cc * 8, &kbuf[sel][c * 8]);
      glds16(vtbase + (size_t)row * S_ + kv0 + cc * 8, &vbuf[sel][c * 8]);
    }
  };

  STAGE(0, 0);
  __syncthreads();

  int sel = 0;
  for (int kv0 = 0; kv0 < S_; kv0 += 64, sel ^= 1) {
    if (kv0 + 64 < S_) STAGE(sel ^ 1, kv0 + 64);

    // ---- S' = (q * log2e/8) K^T : 32 x 64 per wave ----
    f32x4 sc[2][4];
#pragma unroll
    for (int qi = 0; qi < 2; qi++)
#pragma unroll
      for (int cb = 0; cb < 4; cb++) sc[qi][cb] = (f32x4){0.f, 0.f, 0.f, 0.f};
    __builtin_amdgcn_s_setprio(1);
#pragma unroll
    for (int cb = 0; cb < 4; cb++) {
      const int row = cb * 16 + l15;
      const int r7 = row & 7;
      short8 kf0 = *(const short8*)&kbuf[sel][(row * 8 + ((lane >> 4) ^ r7)) * 8];
      short8 kf1 = *(const short8*)&kbuf[sel][(row * 8 + ((4 + (lane >> 4)) ^ r7)) * 8];
#pragma unroll
      for (int qi = 0; qi < 2; qi++) {
        sc[qi][cb] = __builtin_amdgcn_mfma_f32_16x16x32_bf16(qf[qi][0], kf0, sc[qi][cb], 0, 0, 0);
        sc[qi][cb] = __builtin_amdgcn_mfma_f32_16x16x32_bf16(qf[qi][1], kf1, sc[qi][cb], 0, 0, 0);
      }
    }
    __builtin_amdgcn_s_setprio(0);

#pragma unroll
    for (int qi = 0; qi < 2; qi++) {
      // ---- tile row-max (wave-parallel: 16-lane row groups) ----
      float mx[4];
#pragma unroll
      for (int r = 0; r < 4; r++) {
        float v0 = fmaxf(fmaxf(sc[qi][0][r], sc[qi][1][r]), fmaxf(sc[qi][2][r], sc[qi][3][r]));
        v0 = fmaxf(v0, __shfl_xor(v0, 1));
        v0 = fmaxf(v0, __shfl_xor(v0, 2));
        v0 = fmaxf(v0, __shfl_xor(v0, 4));
        v0 = fmaxf(v0, __shfl_xor(v0, 8));
        mx[r] = v0;
      }
      // ---- defer-max: rescale only if some row grew past m + 8*log2e ----
      const float THR = 11.5415603f;  // 8 * log2(e)
      int stable = (mx[0] <= m_r[qi][0] + THR) & (mx[1] <= m_r[qi][1] + THR) &
                   (mx[2] <= m_r[qi][2] + THR) & (mx[3] <= m_r[qi][3] + THR);
      if (!__all(stable)) {
        float fct[4];
#pragma unroll
        for (int r = 0; r < 4; r++) {
          float mn = fmaxf(m_r[qi][r], mx[r]);
          fct[r] = exp2f_fast(m_r[qi][r] - mn);
          m_r[qi][r] = mn;
          l_acc[qi][r] *= fct[r];
        }
#pragma unroll
        for (int cb = 0; cb < 4; cb++)
#pragma unroll
          for (int r = 0; r < 4; r++) o_acc[qi][cb][r] *= fct[r];
      }

      // ---- P = exp2(S' - m') -> bf16 pbuf via v_cvt_pk_bf16_f32 ----
#pragma unroll
      for (int cb = 0; cb < 4; cb++) {
        float e0 = exp2f_fast(sc[qi][cb][0] - m_r[qi][0]);
        float e1 = exp2f_fast(sc[qi][cb][1] - m_r[qi][1]);
        float e2 = exp2f_fast(sc[qi][cb][2] - m_r[qi][2]);
        float e3 = exp2f_fast(sc[qi][cb][3] - m_r[qi][3]);
        uint32_t p01 = cvt_pk_bf16(e0, e1);
        uint32_t p23 = cvt_pk_bf16(e2, e3);
        *pw[0][cb] = (ushort)p01;
        *pw[1][cb] = (ushort)(p01 >> 16);
        *pw[2][cb] = (ushort)p23;
        *pw[3][cb] = (ushort)(p23 >> 16);
      }

      // ---- O += P V, l += P 1 ----
      __builtin_amdgcn_s_setprio(1);
#pragma unroll
      for (int ks = 0; ks < 2; ks++) {
        short8 pf = *(const short8*)pr[ks];
        l_acc[qi] = __builtin_amdgcn_mfma_f32_16x16x32_bf16(pf, onesf, l_acc[qi], 0, 0, 0);
#pragma unroll
        for (int cb = 0; cb < 4; cb++) {
          const int vrow = cb * 16 + l15;
          const int cc = ks * 4 + (lane >> 4);
          short8 vf = *(const short8*)&vbuf[sel][(vrow * 8 + (cc ^ (vrow & 7))) * 8];
          o_acc[qi][cb] = __builtin_amdgcn_mfma_f32_16x16x32_bf16(pf, vf, o_acc[qi][cb], 0, 0, 0);
        }
      }
      __builtin_amdgcn_s_setprio(0);
    }
    __syncthreads();
  }

  // ---- epilogue: O / l -> o[B][S][H*64] (bf16) ----
#pragma unroll
  for (int qi = 0; qi < 2; qi++) {
    float inv[4];
#pragma unroll
    for (int r = 0; r < 4; r++) inv[r] = 1.f / l_acc[qi][r];
    ushort* ob = o + ((size_t)b * S_ + q0 + w * 32 + qi * 16 + prow) * DM + h * HD + l15;
#pragma unroll
    for (int cb = 0; cb < 4; cb++)
#pragma unroll
      for (int r = 0; r < 4; r++)
        ob[(size_t)r * DM + cb * 16] = f2bf(o_acc[qi][cb][r] * inv[r]);
  }
}

// ---------------- launch ----------------
extern "C" void kernel_launch(void* const* d_in, const int* in_sizes, int n_in,
                              void* d_out, int out_size, void* d_ws, size_t ws_size,
                              hipStream_t stream) {
  const float* Q  = (const float*)d_in[0];
  const float* K  = (const float*)d_in[1];
  const float* V  = (const float*)d_in[2];
  const float* Wq = (const float*)d_in[3];
  const float* bq = (const float*)d_in[4];
  const float* Wk = (const float*)d_in[5];
  const float* bk = (const float*)d_in[6];
  const float* Wv = (const float*)d_in[7];
  const float* bv = (const float*)d_in[8];
  const float* Wo = (const float*)d_in[9];
  const float* bo = (const float*)d_in[10];
  float* out = (float*)d_out;
  ushort* ws = (ushort*)d_ws;

  const size_t WN = (size_t)1024 * 1024;       // weight elems
  const size_t PN = (size_t)B_ * S_ * DM;      // activation elems (8.39M)
  ushort* wqT = ws;
  ushort* wkT = ws + WN;
  ushort* wvT = ws + 2 * WN;
  ushort* woT = ws + 3 * WN;
  ushort* qws = ws + 4 * WN;
  ushort* kws = qws + PN;
  ushort* vws = kws + PN;
  ushort* vt  = (ushort*)d_out;  // V^T scratch in d_out (bf16 16.8MB < fp32 33.5MB); overwritten by final GEMM
  ushort* ows = vws;             // v head-split dead after transpose_v; reuse for attention output

  transposeW<<<256, 256, 0, stream>>>(Wq, wqT);
  transposeW<<<256, 256, 0, stream>>>(Wk, wkT);
  transposeW<<<256, 256, 0, stream>>>(Wv, wvT);
  transposeW<<<256, 256, 0, stream>>>(Wo, woT);

  dim3 gg(64, 8);  // M/128 x N/128
  // Q pre-scaled by (1/8)*log2(e): attention scores land in the log2 domain
  gemm_bt<1, 1><<<gg, 256, 0, stream>>>(Q, wqT, bq, qws, 8192, 1024, 1024, 0.18033688f);
  gemm_bt<1, 1><<<gg, 256, 0, stream>>>(K, wkT, bk, kws, 8192, 1024, 1024, 1.0f);
  gemm_bt<1, 1><<<gg, 256, 0, stream>>>(V, wvT, bv, vws, 8192, 1024, 1024, 1.0f);

  transpose_v_k<<<BH * 32, 256, 0, stream>>>(vws, vt);
  attn<<<BH * 16, 256, 0, stream>>>(qws, kws, vt, ows);

  gemm_bt<0, 0><<<gg, 256, 0, stream>>>(ows, woT, bo, out, 8192, 1024, 1024, 1.0f);
}

// Round 2
// 258.441 us; speedup vs baseline: 1.3031x; 1.2330x over previous
//
#include <hip/hip_runtime.h>
#include <hip/hip_bf16.h>
#include <stdint.h>

// MHA: B=4, S=2048, D_MODEL=1024, H=16, hd=64.
// Interface: fp32 in / fp32 out. Internal compute: bf16 MFMA.

#define B_  4
#define S_  2048
#define DM  1024
#define H_  16
#define HD  64
#define BH  (B_ * H_)

typedef __attribute__((ext_vector_type(8))) short short8;
typedef __attribute__((ext_vector_type(4))) float f32x4;

union U8 { short8 v; ushort u[8]; };

__device__ __forceinline__ ushort f2bf(float f) {
  union { float f; uint32_t i; } x; x.f = f;
  uint32_t r = (x.i + 0x7FFFu + ((x.i >> 16) & 1u)) >> 16;
  return (ushort)r;
}

// packed f32x2 -> bf16x2 (RNE), gfx950 hw convert; no builtin exists (m240)
__device__ __forceinline__ uint32_t cvt_pk_bf16(float a, float b) {
  uint32_t r;
  asm("v_cvt_pk_bf16_f32 %0, %1, %2" : "=v"(r) : "v"(a), "v"(b));
  return r;
}

// raw 2^x (v_exp_f32 IS exp2)
__device__ __forceinline__ float exp2f_fast(float x) {
  float r;
  asm("v_exp_f32 %0, %1" : "=v"(r) : "v"(x));
  return r;
}

__device__ __forceinline__ void glds16(const ushort* g, ushort* l) {
  __builtin_amdgcn_global_load_lds(
      (const __attribute__((address_space(1))) void*)g,
      (__attribute__((address_space(3))) void*)l, 16, 0, 0);
}

// ---------------- weight ingest: fp32 [1024][1024] -> bf16 transposed ----------------
__global__ __launch_bounds__(256) void transposeW(const float* __restrict__ src,
                                                  ushort* __restrict__ dst) {
  __shared__ __align__(16) ushort tile[64][72];
  const int t = threadIdx.x;
  const int bx = blockIdx.x & 15;   // src col block
  const int by = blockIdx.x >> 4;   // src row block
#pragma unroll
  for (int i = 0; i < 2; i++) {
    int e = (i * 256 + t) * 8;
    int r = e >> 6, c = e & 63;
    const float* sp = src + (size_t)(by * 64 + r) * 1024 + bx * 64 + c;
    float4 a = ((const float4*)sp)[0];
    float4 b = ((const float4*)sp)[1];
    tile[r][c + 0] = f2bf(a.x); tile[r][c + 1] = f2bf(a.y);
    tile[r][c + 2] = f2bf(a.z); tile[r][c + 3] = f2bf(a.w);
    tile[r][c + 4] = f2bf(b.x); tile[r][c + 5] = f2bf(b.y);
    tile[r][c + 6] = f2bf(b.z); tile[r][c + 7] = f2bf(b.w);
  }
  __syncthreads();
#pragma unroll
  for (int i = 0; i < 2; i++) {
    int e = (i * 256 + t) * 8;
    int r = e >> 6, c = e & 63;
    U8 st;
#pragma unroll
    for (int j = 0; j < 8; j++) st.u[j] = tile[c + j][r];
    *(short8*)(dst + (size_t)(bx * 64 + r) * 1024 + by * 64 + c) = st.v;
  }
}

// ---------------- per-head V transpose: bf16 [BH][S][64] -> [BH][64][S] ----------------
__global__ __launch_bounds__(256) void transpose_v_k(const ushort* __restrict__ v,
                                                     ushort* __restrict__ vt) {
  __shared__ __align__(16) ushort tile[64][72];
  const int t = threadIdx.x;
  const int bh = blockIdx.x >> 5;
  const int s0 = (blockIdx.x & 31) * 64;
  const ushort* src = v + (size_t)bh * S_ * HD;
  ushort* dst = vt + (size_t)bh * HD * S_;
#pragma unroll
  for (int i = 0; i < 2; i++) {
    int e = (i * 256 + t) * 8;
    int r = e >> 6, c = e & 63;            // r: s-local, c: d
    U8 ld;
    ld.v = *(const short8*)(src + (size_t)(s0 + r) * HD + c);
#pragma unroll
    for (int j = 0; j < 8; j++) tile[r][c + j] = ld.u[j];
  }
  __syncthreads();
#pragma unroll
  for (int i = 0; i < 2; i++) {
    int e = (i * 256 + t) * 8;
    int r = e >> 6, c = e & 63;            // r: d, c: s-local
    U8 st;
#pragma unroll
    for (int j = 0; j < 8; j++) st.u[j] = tile[c + j][r];
    *(short8*)(dst + (size_t)r * S_ + s0 + c) = st.v;
  }
}

// ---------------- GEMM: C[M][N] = A[M][K] * BT[N][K]^T + bias ----------------
// AFP32: A is fp32 (reg-staged + cvt), else bf16 via global_load_lds.
// CMODE 0: fp32 row-major out. CMODE 1: bf16 head-split [B][H][S][64] out.
template<int AFP32, int CMODE>
__global__ __launch_bounds__(256, 2) void gemm_bt(
    const void* __restrict__ Ap, const ushort* __restrict__ BT,
    const float* __restrict__ bias, void* __restrict__ Cp,
    int M, int N, int K, float oscale) {
  __shared__ __align__(16) ushort lA[128 * 32];
  __shared__ __align__(16) ushort lB[128 * 32];
  const int t = threadIdx.x;
  const int lane = t & 63;
  const int w = t >> 6;
  const int wr = w >> 1, wc = w & 1;
  const int bm0 = blockIdx.x * 128;
  const int bn0 = blockIdx.y * 128;
  f32x4 acc[4][4] = {};

  const int arow = t >> 2;           // 0..63
  const int acol = (t & 3) * 8;      // element offset within 32-wide K slab
  const ushort* gA0 = (const ushort*)Ap + (size_t)(bm0 + arow) * K + acol;
  const ushort* gA1 = (const ushort*)Ap + (size_t)(bm0 + 64 + arow) * K + acol;
  const float*  fA0 = (const float*)Ap + (size_t)(bm0 + arow) * K + acol;
  const float*  fA1 = (const float*)Ap + (size_t)(bm0 + 64 + arow) * K + acol;
  const ushort* gB0 = BT + (size_t)(bn0 + arow) * K + acol;
  const ushort* gB1 = BT + (size_t)(bn0 + 64 + arow) * K + acol;

  for (int k0 = 0; k0 < K; k0 += 32) {
    if (k0) __syncthreads();
    if constexpr (AFP32) {
      float4 x0 = ((const float4*)(fA0 + k0))[0];
      float4 x1 = ((const float4*)(fA0 + k0))[1];
      float4 y0 = ((const float4*)(fA1 + k0))[0];
      float4 y1 = ((const float4*)(fA1 + k0))[1];
      U8 s0, s1;
      s0.u[0] = f2bf(x0.x); s0.u[1] = f2bf(x0.y); s0.u[2] = f2bf(x0.z); s0.u[3] = f2bf(x0.w);
      s0.u[4] = f2bf(x1.x); s0.u[5] = f2bf(x1.y); s0.u[6] = f2bf(x1.z); s0.u[7] = f2bf(x1.w);
      s1.u[0] = f2bf(y0.x); s1.u[1] = f2bf(y0.y); s1.u[2] = f2bf(y0.z); s1.u[3] = f2bf(y0.w);
      s1.u[4] = f2bf(y1.x); s1.u[5] = f2bf(y1.y); s1.u[6] = f2bf(y1.z); s1.u[7] = f2bf(y1.w);
      *(short8*)&lA[t * 8] = s0.v;
      *(short8*)&lA[2048 + t * 8] = s1.v;
    } else {
      glds16(gA0 + k0, &lA[t * 8]);
      glds16(gA1 + k0, &lA[2048 + t * 8]);
    }
    glds16(gB0 + k0, &lB[t * 8]);
    glds16(gB1 + k0, &lB[2048 + t * 8]);
    __syncthreads();
    short8 af[4], bf[4];
#pragma unroll
    for (int i = 0; i < 4; i++)
      af[i] = *(const short8*)&lA[(wr * 64 + i * 16 + (lane & 15)) * 32 + (lane >> 4) * 8];
#pragma unroll
    for (int j = 0; j < 4; j++)
      bf[j] = *(const short8*)&lB[(wc * 64 + j * 16 + (lane & 15)) * 32 + (lane >> 4) * 8];
#pragma unroll
    for (int i = 0; i < 4; i++)
#pragma unroll
      for (int j = 0; j < 4; j++)
        acc[i][j] = __builtin_amdgcn_mfma_f32_16x16x32_bf16(af[i], bf[j], acc[i][j], 0, 0, 0);
  }

  const int r0 = (lane >> 4) * 4;
#pragma unroll
  for (int j = 0; j < 4; j++) {
    const int col = bn0 + wc * 64 + j * 16 + (lane & 15);
    const float bc = bias[col];
#pragma unroll
    for (int i = 0; i < 4; i++) {
      const int row = bm0 + wr * 64 + i * 16 + r0;
#pragma unroll
      for (int r = 0; r < 4; r++) {
        float val = (acc[i][j][r] + bc) * oscale;
        if constexpr (CMODE == 0) {
          ((float*)Cp)[(size_t)(row + r) * N + col] = val;
        } else {
          int rr = row + r;
          int b = rr >> 11, s = rr & 2047;
          int h = col >> 6, d = col & 63;
          ((ushort*)Cp)[(((size_t)b * H_ + h) * S_ + s) * HD + d] = f2bf(val);
        }
      }
    }
  }
}

// ---------------- flash attention (swapped-QK^T, fully in-register P) ----------------
// q,k: bf16 [BH][S][64] (q pre-scaled by log2(e)/8), vt: bf16 [BH][64][S], o: bf16 [B][S][1024]
// Block: 256 threads (4 waves), Q-tile 128 rows (32/wave). KV tile 64.
// Swapped QK^T: sc = mfma(K, Q) = S^T -> each lane owns ONE q-row (col = lane&15).
//   Row-max: in-lane 15-fmax tree + 2 shfl_xor. m/l/rescale are per-lane scalars.
// P stays in registers: MFMA k-dim permuted as k(x)=32ks+16(j>>2)+4(x>>3)+(x&3), which
//   matches the natural cvt_pk word locations (zero cross-lane movement); the V^T
//   A-fragment compensates by reading two 8B chunks per (ks,cb) from vbuf.
// O accumulates transposed: lane holds 4 consecutive d per cb -> packed 8B stores.
// LDS = 16K(kbuf)+16K(vbuf) = 32768 B.
__global__ __launch_bounds__(256, 4) void attn(
    const ushort* __restrict__ q, const ushort* __restrict__ k,
    const ushort* __restrict__ vt, ushort* __restrict__ o) {
  __shared__ __align__(16) ushort kbuf[2][4096];
  __shared__ __align__(16) ushort vbuf[2][4096];
  const int t = threadIdx.x;
  const int lane = t & 63;
  const int w = t >> 6;
  // XCD-bijective swizzle: 1024 blocks, 16 q-tiles/head -> one head's blocks share an XCD L2
  const int L = ((blockIdx.x & 7) << 7) + (blockIdx.x >> 3);
  const int bh = L >> 4;
  const int q0 = (L & 15) * 128;
  const int b = bh >> 4, h = bh & 15;
  const int l15 = lane & 15;
  const int g = lane >> 4;

  const ushort* kbase  = k  + (size_t)bh * S_ * HD;
  const ushort* vtbase = vt + (size_t)bh * HD * S_;

  // Q fragments: 32 rows per wave, hd=64 in two x-slabs (used as MFMA B operand)
  short8 qf[2][2];
#pragma unroll
  for (int qi = 0; qi < 2; qi++) {
    const ushort* qp = q + ((size_t)bh * S_ + q0 + w * 32 + qi * 16 + l15) * HD + g * 8;
    qf[qi][0] = *(const short8*)qp;
    qf[qi][1] = *(const short8*)(qp + 32);
  }

  // ones A-fragment for l accumulation (bf16 1.0 = 0x3F80)
  short8 onesf;
#pragma unroll
  for (int j = 0; j < 8; j++) onesf[j] = (short)0x3F80;

  float m_r[2] = {-1e30f, -1e30f};
  f32x4 l_acc[2];
  f32x4 o_acc[2][4];
#pragma unroll
  for (int qi = 0; qi < 2; qi++) {
    l_acc[qi] = (f32x4){0.f, 0.f, 0.f, 0.f};
#pragma unroll
    for (int cb = 0; cb < 4; cb++) o_acc[qi][cb] = (f32x4){0.f, 0.f, 0.f, 0.f};
  }

  // stage one 64-kv tile (K 64x64 row-major, Vt 64x64 row-major) with XOR-swizzled source
  auto STAGE = [&](int sel, int kv0) {
#pragma unroll
    for (int i = 0; i < 2; i++) {
      int c = i * 256 + t;            // 16B-chunk index, 512 chunks per tile
      int row = c >> 3;
      int cc = (c & 7) ^ (row & 7);   // pre-swizzled source chunk
      glds16(kbase + (size_t)(kv0 + row) * HD + cc * 8, &kbuf[sel][c * 8]);
      glds16(vtbase + (size_t)row * S_ + kv0 + cc * 8, &vbuf[sel][c * 8]);
    }
  };

  STAGE(0, 0);
  __syncthreads();

  int sel = 0;
  for (int kv0 = 0; kv0 < S_; kv0 += 64, sel ^= 1) {
    if (kv0 + 64 < S_) STAGE(sel ^ 1, kv0 + 64);

    // ---- S^T = K (Q*log2e/8)^T : lane holds k-rows (4g+r per cb) of q-col l15 ----
    f32x4 sc[2][4];
#pragma unroll
    for (int qi = 0; qi < 2; qi++)
#pragma unroll
      for (int cb = 0; cb < 4; cb++) sc[qi][cb] = (f32x4){0.f, 0.f, 0.f, 0.f};
    __builtin_amdgcn_s_setprio(1);
#pragma unroll
    for (int cb = 0; cb < 4; cb++) {
      const int row = cb * 16 + l15;
      const int r7 = row & 7;
      short8 kf0 = *(const short8*)&kbuf[sel][(row * 8 + (g ^ r7)) * 8];
      short8 kf1 = *(const short8*)&kbuf[sel][(row * 8 + ((4 + g) ^ r7)) * 8];
#pragma unroll
      for (int qi = 0; qi < 2; qi++) {
        sc[qi][cb] = __builtin_amdgcn_mfma_f32_16x16x32_bf16(kf0, qf[qi][0], sc[qi][cb], 0, 0, 0);
        sc[qi][cb] = __builtin_amdgcn_mfma_f32_16x16x32_bf16(kf1, qf[qi][1], sc[qi][cb], 0, 0, 0);
      }
    }
    __builtin_amdgcn_s_setprio(0);

#pragma unroll
    for (int qi = 0; qi < 2; qi++) {
      // ---- in-lane row-max over 16 values + 2-shfl group reduce ----
      float a0 = fmaxf(sc[qi][0][0], sc[qi][0][1]);
      float a1 = fmaxf(sc[qi][0][2], sc[qi][0][3]);
      float a2 = fmaxf(sc[qi][1][0], sc[qi][1][1]);
      float a3 = fmaxf(sc[qi][1][2], sc[qi][1][3]);
      float a4 = fmaxf(sc[qi][2][0], sc[qi][2][1]);
      float a5 = fmaxf(sc[qi][2][2], sc[qi][2][3]);
      float a6 = fmaxf(sc[qi][3][0], sc[qi][3][1]);
      float a7 = fmaxf(sc[qi][3][2], sc[qi][3][3]);
      float b0 = fmaxf(fmaxf(a0, a1), fmaxf(a2, a3));
      float b1 = fmaxf(fmaxf(a4, a5), fmaxf(a6, a7));
      float mx = fmaxf(b0, b1);
      mx = fmaxf(mx, __shfl_xor(mx, 16));
      mx = fmaxf(mx, __shfl_xor(mx, 32));

      // ---- defer-max (per-lane scalar m): rescale only if max grew past m + 8*log2e ----
      const float THR = 11.5415603f;  // 8 * log2(e)
      if (!__all(mx <= m_r[qi] + THR)) {
        float mn = fmaxf(m_r[qi], mx);
        float fct = exp2f_fast(m_r[qi] - mn);
        m_r[qi] = mn;
        l_acc[qi] *= fct;
#pragma unroll
        for (int cb = 0; cb < 4; cb++)
#pragma unroll
          for (int r = 0; r < 4; r++) o_acc[qi][cb][r] *= fct;
      }

      // ---- P = exp2(S - m) packed to bf16 words, all in-lane ----
      uint32_t W[4][2];
      const float m = m_r[qi];
#pragma unroll
      for (int cb = 0; cb < 4; cb++) {
        float p0 = exp2f_fast(sc[qi][cb][0] - m);
        float p1 = exp2f_fast(sc[qi][cb][1] - m);
        float p2 = exp2f_fast(sc[qi][cb][2] - m);
        float p3 = exp2f_fast(sc[qi][cb][3] - m);
        W[cb][0] = cvt_pk_bf16(p0, p1);
        W[cb][1] = cvt_pk_bf16(p2, p3);
      }

      // ---- O^T += V^T P^T (k-dim permuted to match in-lane P words), l += 1.P ----
      __builtin_amdgcn_s_setprio(1);
#pragma unroll
      for (int ks = 0; ks < 2; ks++) {
        union { short8 v; uint32_t u[4]; } pb;
        pb.u[0] = W[2 * ks][0];
        pb.u[1] = W[2 * ks][1];
        pb.u[2] = W[2 * ks + 1][0];
        pb.u[3] = W[2 * ks + 1][1];
        l_acc[qi] = __builtin_amdgcn_mfma_f32_16x16x32_bf16(onesf, pb.v, l_acc[qi], 0, 0, 0);
#pragma unroll
        for (int cb = 0; cb < 4; cb++) {
          const int vrow = cb * 16 + l15;
          const int r7v = vrow & 7;
          const ushort* vb = &vbuf[sel][vrow * 64];
          union { short8 v; uint2 d2[2]; } vv;
          vv.d2[0] = *(const uint2*)(vb + ((4 * ks + (g >> 1)) ^ r7v) * 8 + (g & 1) * 4);
          vv.d2[1] = *(const uint2*)(vb + ((4 * ks + 2 + (g >> 1)) ^ r7v) * 8 + (g & 1) * 4);
          o_acc[qi][cb] = __builtin_amdgcn_mfma_f32_16x16x32_bf16(vv.v, pb.v, o_acc[qi][cb], 0, 0, 0);
        }
      }
      __builtin_amdgcn_s_setprio(0);
    }
    __syncthreads();
  }

  // ---- epilogue: O^T / l -> o[B][S][H*64] (bf16, packed 8B stores) ----
#pragma unroll
  for (int qi = 0; qi < 2; qi++) {
    const float inv = 1.f / l_acc[qi][0];
    ushort* ob = o + ((size_t)b * S_ + q0 + w * 32 + qi * 16 + l15) * DM + h * HD + 4 * g;
#pragma unroll
    for (int cb = 0; cb < 4; cb++) {
      uint2 st;
      st.x = cvt_pk_bf16(o_acc[qi][cb][0] * inv, o_acc[qi][cb][1] * inv);
      st.y = cvt_pk_bf16(o_acc[qi][cb][2] * inv, o_acc[qi][cb][3] * inv);
      *(uint2*)(ob + cb * 16) = st;
    }
  }
}

// ---------------- launch ----------------
extern "C" void kernel_launch(void* const* d_in, const int* in_sizes, int n_in,
                              void* d_out, int out_size, void* d_ws, size_t ws_size,
                              hipStream_t stream) {
  const float* Q  = (const float*)d_in[0];
  const float* K  = (const float*)d_in[1];
  const float* V  = (const float*)d_in[2];
  const float* Wq = (const float*)d_in[3];
  const float* bq = (const float*)d_in[4];
  const float* Wk = (const float*)d_in[5];
  const float* bk = (const float*)d_in[6];
  const float* Wv = (const float*)d_in[7];
  const float* bv = (const float*)d_in[8];
  const float* Wo = (const float*)d_in[9];
  const float* bo = (const float*)d_in[10];
  float* out = (float*)d_out;
  ushort* ws = (ushort*)d_ws;

  const size_t WN = (size_t)1024 * 1024;       // weight elems
  const size_t PN = (size_t)B_ * S_ * DM;      // activation elems (8.39M)
  ushort* wqT = ws;
  ushort* wkT = ws + WN;
  ushort* wvT = ws + 2 * WN;
  ushort* woT = ws + 3 * WN;
  ushort* qws = ws + 4 * WN;
  ushort* kws = qws + PN;
  ushort* vws = kws + PN;
  ushort* vt  = (ushort*)d_out;  // V^T scratch in d_out (bf16 16.8MB < fp32 33.5MB); overwritten by final GEMM
  ushort* ows = vws;             // v head-split dead after transpose_v; reuse for attention output

  transposeW<<<256, 256, 0, stream>>>(Wq, wqT);
  transposeW<<<256, 256, 0, stream>>>(Wk, wkT);
  transposeW<<<256, 256, 0, stream>>>(Wv, wvT);
  transposeW<<<256, 256, 0, stream>>>(Wo, woT);

  dim3 gg(64, 8);  // M/128 x N/128
  // Q pre-scaled by (1/8)*log2(e): attention scores land in the log2 domain
  gemm_bt<1, 1><<<gg, 256, 0, stream>>>(Q, wqT, bq, qws, 8192, 1024, 1024, 0.18033688f);
  gemm_bt<1, 1><<<gg, 256, 0, stream>>>(K, wkT, bk, kws, 8192, 1024, 1024, 1.0f);
  gemm_bt<1, 1><<<gg, 256, 0, stream>>>(V, wvT, bv, vws, 8192, 1024, 1024, 1.0f);

  transpose_v_k<<<BH * 32, 256, 0, stream>>>(vws, vt);
  attn<<<BH * 16, 256, 0, stream>>>(qws, kws, vt, ows);

  gemm_bt<0, 0><<<gg, 256, 0, stream>>>(ows, woT, bo, out, 8192, 1024, 1024, 1.0f);
}

// Round 3
// 236.112 us; speedup vs baseline: 1.4263x; 1.0946x over previous
//
#include <hip/hip_runtime.h>
#include <hip/hip_bf16.h>
#include <stdint.h>

// MHA: B=4, S=2048, D_MODEL=1024, H=16, hd=64.
// Interface: fp32 in / fp32 out. Internal compute: bf16 MFMA.

#define B_  4
#define S_  2048
#define DM  1024
#define H_  16
#define HD  64
#define BH  (B_ * H_)

typedef __attribute__((ext_vector_type(8))) short short8;
typedef __attribute__((ext_vector_type(4))) float f32x4;

union U8 { short8 v; ushort u[8]; };

__device__ __forceinline__ ushort f2bf(float f) {
  union { float f; uint32_t i; } x; x.f = f;
  uint32_t r = (x.i + 0x7FFFu + ((x.i >> 16) & 1u)) >> 16;
  return (ushort)r;
}

// packed f32x2 -> bf16x2 (RNE), gfx950 hw convert; no builtin exists (m240)
__device__ __forceinline__ uint32_t cvt_pk_bf16(float a, float b) {
  uint32_t r;
  asm("v_cvt_pk_bf16_f32 %0, %1, %2" : "=v"(r) : "v"(a), "v"(b));
  return r;
}

// raw 2^x (v_exp_f32 IS exp2)
__device__ __forceinline__ float exp2f_fast(float x) {
  float r;
  asm("v_exp_f32 %0, %1" : "=v"(r) : "v"(x));
  return r;
}

__device__ __forceinline__ void glds16(const ushort* g, ushort* l) {
  __builtin_amdgcn_global_load_lds(
      (const __attribute__((address_space(1))) void*)g,
      (__attribute__((address_space(3))) void*)l, 16, 0, 0);
}

#define MAX3(a, b, c) fmaxf(fmaxf((a), (b)), (c))

// ---------------- weight ingest: fp32 [1024][1024] -> bf16 transposed ----------------
__global__ __launch_bounds__(256) void transposeW(const float* __restrict__ src,
                                                  ushort* __restrict__ dst) {
  __shared__ __align__(16) ushort tile[64][72];
  const int t = threadIdx.x;
  const int bx = blockIdx.x & 15;   // src col block
  const int by = blockIdx.x >> 4;   // src row block
#pragma unroll
  for (int i = 0; i < 2; i++) {
    int e = (i * 256 + t) * 8;
    int r = e >> 6, c = e & 63;
    const float* sp = src + (size_t)(by * 64 + r) * 1024 + bx * 64 + c;
    float4 a = ((const float4*)sp)[0];
    float4 b = ((const float4*)sp)[1];
    tile[r][c + 0] = f2bf(a.x); tile[r][c + 1] = f2bf(a.y);
    tile[r][c + 2] = f2bf(a.z); tile[r][c + 3] = f2bf(a.w);
    tile[r][c + 4] = f2bf(b.x); tile[r][c + 5] = f2bf(b.y);
    tile[r][c + 6] = f2bf(b.z); tile[r][c + 7] = f2bf(b.w);
  }
  __syncthreads();
#pragma unroll
  for (int i = 0; i < 2; i++) {
    int e = (i * 256 + t) * 8;
    int r = e >> 6, c = e & 63;
    U8 st;
#pragma unroll
    for (int j = 0; j < 8; j++) st.u[j] = tile[c + j][r];
    *(short8*)(dst + (size_t)(bx * 64 + r) * 1024 + by * 64 + c) = st.v;
  }
}

// ---------------- GEMM: C[M][N] = A[M][K] * BT[N][K]^T + bias ----------------
// AFP32: A is fp32 (reg-staged + cvt_pk), else bf16 via global_load_lds.
// CMODE 0: fp32 row-major out.
// CMODE 1: bf16 head-split [B][H][S][64] out.
// CMODE 2: bf16 V^T [BH][64][S] out with 8B-subchunk swizzle (phys = logical ^ (d&15))
//          baked per 64-col block -> attn stages vbuf with a LINEAR copy.
template<int AFP32, int CMODE>
__global__ __launch_bounds__(256, 2) void gemm_bt(
    const void* __restrict__ Ap, const ushort* __restrict__ BT,
    const float* __restrict__ bias, void* __restrict__ Cp,
    int M, int N, int K, float oscale) {
  __shared__ __align__(16) ushort lA[128 * 32];
  __shared__ __align__(16) ushort lB[128 * 32];
  const int t = threadIdx.x;
  const int lane = t & 63;
  const int w = t >> 6;
  const int wr = w >> 1, wc = w & 1;
  const int bm0 = blockIdx.x * 128;
  const int bn0 = blockIdx.y * 128;
  f32x4 acc[4][4] = {};

  const int arow = t >> 2;           // 0..63
  const int acol = (t & 3) * 8;      // element offset within 32-wide K slab
  const ushort* gA0 = (const ushort*)Ap + (size_t)(bm0 + arow) * K + acol;
  const ushort* gA1 = (const ushort*)Ap + (size_t)(bm0 + 64 + arow) * K + acol;
  const float*  fA0 = (const float*)Ap + (size_t)(bm0 + arow) * K + acol;
  const float*  fA1 = (const float*)Ap + (size_t)(bm0 + 64 + arow) * K + acol;
  const ushort* gB0 = BT + (size_t)(bn0 + arow) * K + acol;
  const ushort* gB1 = BT + (size_t)(bn0 + 64 + arow) * K + acol;

  for (int k0 = 0; k0 < K; k0 += 32) {
    if (k0) __syncthreads();
    if constexpr (AFP32) {
      float4 x0 = ((const float4*)(fA0 + k0))[0];
      float4 x1 = ((const float4*)(fA0 + k0))[1];
      float4 y0 = ((const float4*)(fA1 + k0))[0];
      float4 y1 = ((const float4*)(fA1 + k0))[1];
      union { short8 v; uint32_t u[4]; } s0, s1;
      s0.u[0] = cvt_pk_bf16(x0.x, x0.y); s0.u[1] = cvt_pk_bf16(x0.z, x0.w);
      s0.u[2] = cvt_pk_bf16(x1.x, x1.y); s0.u[3] = cvt_pk_bf16(x1.z, x1.w);
      s1.u[0] = cvt_pk_bf16(y0.x, y0.y); s1.u[1] = cvt_pk_bf16(y0.z, y0.w);
      s1.u[2] = cvt_pk_bf16(y1.x, y1.y); s1.u[3] = cvt_pk_bf16(y1.z, y1.w);
      *(short8*)&lA[t * 8] = s0.v;
      *(short8*)&lA[2048 + t * 8] = s1.v;
    } else {
      glds16(gA0 + k0, &lA[t * 8]);
      glds16(gA1 + k0, &lA[2048 + t * 8]);
    }
    glds16(gB0 + k0, &lB[t * 8]);
    glds16(gB1 + k0, &lB[2048 + t * 8]);
    __syncthreads();
    short8 af[4], bf[4];
#pragma unroll
    for (int i = 0; i < 4; i++)
      af[i] = *(const short8*)&lA[(wr * 64 + i * 16 + (lane & 15)) * 32 + (lane >> 4) * 8];
#pragma unroll
    for (int j = 0; j < 4; j++)
      bf[j] = *(const short8*)&lB[(wc * 64 + j * 16 + (lane & 15)) * 32 + (lane >> 4) * 8];
#pragma unroll
    for (int i = 0; i < 4; i++)
#pragma unroll
      for (int j = 0; j < 4; j++)
        acc[i][j] = __builtin_amdgcn_mfma_f32_16x16x32_bf16(af[i], bf[j], acc[i][j], 0, 0, 0);
  }

  const int r0 = (lane >> 4) * 4;
#pragma unroll
  for (int j = 0; j < 4; j++) {
    const int col = bn0 + wc * 64 + j * 16 + (lane & 15);
    const float bc = bias[col];
#pragma unroll
    for (int i = 0; i < 4; i++) {
      const int row = bm0 + wr * 64 + i * 16 + r0;   // row % 4 == 0
      if constexpr (CMODE == 2) {
        // V^T swizzled: 4 consecutive s = one 8B sub-chunk
        const int bb = row >> 11, s = row & 2047;
        const int hh = col >> 6, d = col & 63;
        uint32_t p01 = cvt_pk_bf16((acc[i][j][0] + bc) * oscale, (acc[i][j][1] + bc) * oscale);
        uint32_t p23 = cvt_pk_bf16((acc[i][j][2] + bc) * oscale, (acc[i][j][3] + bc) * oscale);
        ushort* vtb = (ushort*)Cp + (((size_t)bb * H_ + hh) * HD + d) * (size_t)S_;
        const int sc = (s & 63) >> 2;                // logical 8B sub-chunk in 64-col block
        *(uint2*)(vtb + (s & ~63) + ((sc ^ (d & 15)) << 2)) = (uint2){p01, p23};
      } else {
#pragma unroll
        for (int r = 0; r < 4; r++) {
          float val = (acc[i][j][r] + bc) * oscale;
          if constexpr (CMODE == 0) {
            ((float*)Cp)[(size_t)(row + r) * N + col] = val;
          } else {
            int rr = row + r;
            int b = rr >> 11, s = rr & 2047;
            int h = col >> 6, d = col & 63;
            ((ushort*)Cp)[(((size_t)b * H_ + h) * S_ + s) * HD + d] = f2bf(val);
          }
        }
      }
    }
  }
}

// ---------------- flash attention (swapped-QK^T, fully in-register P) ----------------
// q,k: bf16 [BH][S][64] (q pre-scaled by log2(e)/8), vt: bf16 [BH][64][S] 8B-swizzled,
// o: bf16 [B][S][1024]
// Block: 256 threads (4 waves), Q-tile 128 rows (32/wave). KV tile 64.
// Swapped QK^T: sc = mfma(K, Q) = S^T -> each lane owns ONE q-row (col = lane&15).
// P stays in registers (k-dim permutation matches cvt_pk word placement).
// V-read: two ds_read_b64 per (ks,cb); 8B-subchunk swizzle keyed on d&15 makes each
//   16-lane phase cover all 32 banks exactly once (R2's d&7/16B swizzle left 2-way
//   conflicts: 16.78M counter = 1/phase). Swizzle is baked in vt -> STAGE is linear.
// LDS = 16K(kbuf)+16K(vbuf) = 32768 B.
__global__ __launch_bounds__(256, 4) void attn(
    const ushort* __restrict__ q, const ushort* __restrict__ k,
    const ushort* __restrict__ vt, ushort* __restrict__ o) {
  __shared__ __align__(16) ushort kbuf[2][4096];
  __shared__ __align__(16) ushort vbuf[2][4096];
  const int t = threadIdx.x;
  const int lane = t & 63;
  const int w = t >> 6;
  // XCD-bijective swizzle: 1024 blocks, 16 q-tiles/head -> one head's blocks share an XCD L2
  const int L = ((blockIdx.x & 7) << 7) + (blockIdx.x >> 3);
  const int bh = L >> 4;
  const int q0 = (L & 15) * 128;
  const int b = bh >> 4, h = bh & 15;
  const int l15 = lane & 15;
  const int g = lane >> 4;

  const ushort* kbase  = k  + (size_t)bh * S_ * HD;
  const ushort* vtbase = vt + (size_t)bh * HD * S_;

  // Q fragments: 32 rows per wave, hd=64 in two x-slabs (used as MFMA B operand)
  short8 qf[2][2];
#pragma unroll
  for (int qi = 0; qi < 2; qi++) {
    const ushort* qp = q + ((size_t)bh * S_ + q0 + w * 32 + qi * 16 + l15) * HD + g * 8;
    qf[qi][0] = *(const short8*)qp;
    qf[qi][1] = *(const short8*)(qp + 32);
  }

  // ones A-fragment for l accumulation (bf16 1.0 = 0x3F80)
  short8 onesf;
#pragma unroll
  for (int j = 0; j < 8; j++) onesf[j] = (short)0x3F80;

  float m_r[2] = {-1e30f, -1e30f};
  f32x4 l_acc[2];
  f32x4 o_acc[2][4];
#pragma unroll
  for (int qi = 0; qi < 2; qi++) {
    l_acc[qi] = (f32x4){0.f, 0.f, 0.f, 0.f};
#pragma unroll
    for (int cb = 0; cb < 4; cb++) o_acc[qi][cb] = (f32x4){0.f, 0.f, 0.f, 0.f};
  }

  // V-read sub-chunk offsets (ushort units), loop/cb-invariant: (8ks+g+{0,4}) ^ l15
  int vo[2][2];
#pragma unroll
  for (int ks = 0; ks < 2; ks++) {
    vo[ks][0] = ((8 * ks + g) ^ l15) << 2;
    vo[ks][1] = ((8 * ks + 4 + g) ^ l15) << 2;
  }

  // stage one 64-kv tile: K with XOR-swizzled source (16B chunks), V linear (pre-swizzled in vt)
  auto STAGE = [&](int sel_, int kv0) {
#pragma unroll
    for (int i = 0; i < 2; i++) {
      int c = i * 256 + t;            // 16B-chunk index, 512 chunks per tile
      int row = c >> 3;
      int cc = (c & 7) ^ (row & 7);   // pre-swizzled source chunk (K only)
      glds16(kbase + (size_t)(kv0 + row) * HD + cc * 8, &kbuf[sel_][c * 8]);
      glds16(vtbase + (size_t)row * S_ + kv0 + (c & 7) * 8, &vbuf[sel_][c * 8]);
    }
  };

  STAGE(0, 0);
  __syncthreads();

  int sel = 0;
  for (int kv0 = 0; kv0 < S_; kv0 += 64, sel ^= 1) {
    if (kv0 + 64 < S_) STAGE(sel ^ 1, kv0 + 64);

    // ---- S^T = K (Q*log2e/8)^T : lane holds k-rows (4g+r per cb) of q-col l15 ----
    f32x4 sc[2][4];
#pragma unroll
    for (int qi = 0; qi < 2; qi++)
#pragma unroll
      for (int cb = 0; cb < 4; cb++) sc[qi][cb] = (f32x4){0.f, 0.f, 0.f, 0.f};
    __builtin_amdgcn_s_setprio(1);
#pragma unroll
    for (int cb = 0; cb < 4; cb++) {
      const int row = cb * 16 + l15;
      const int r7 = row & 7;
      short8 kf0 = *(const short8*)&kbuf[sel][(row * 8 + (g ^ r7)) * 8];
      short8 kf1 = *(const short8*)&kbuf[sel][(row * 8 + ((4 + g) ^ r7)) * 8];
#pragma unroll
      for (int qi = 0; qi < 2; qi++) {
        sc[qi][cb] = __builtin_amdgcn_mfma_f32_16x16x32_bf16(kf0, qf[qi][0], sc[qi][cb], 0, 0, 0);
        sc[qi][cb] = __builtin_amdgcn_mfma_f32_16x16x32_bf16(kf1, qf[qi][1], sc[qi][cb], 0, 0, 0);
      }
    }
    __builtin_amdgcn_s_setprio(0);

#pragma unroll
    for (int qi = 0; qi < 2; qi++) {
      // ---- in-lane row-max over 16 values (v_max3 tree) + 2-shfl group reduce ----
      float z0 = MAX3(sc[qi][0][0], sc[qi][0][1], sc[qi][0][2]);
      float z1 = MAX3(sc[qi][0][3], sc[qi][1][0], sc[qi][1][1]);
      float z2 = MAX3(sc[qi][1][2], sc[qi][1][3], sc[qi][2][0]);
      float z3 = MAX3(sc[qi][2][1], sc[qi][2][2], sc[qi][2][3]);
      float z4 = MAX3(sc[qi][3][0], sc[qi][3][1], sc[qi][3][2]);
      float mx = MAX3(MAX3(z0, z1, z2), fmaxf(z3, z4), sc[qi][3][3]);
      mx = fmaxf(mx, __shfl_xor(mx, 16));
      mx = fmaxf(mx, __shfl_xor(mx, 32));

      // ---- defer-max (per-lane scalar m): rescale only if max grew past m + 8*log2e ----
      const float THR = 11.5415603f;  // 8 * log2(e)
      if (!__all(mx <= m_r[qi] + THR)) {
        float mn = fmaxf(m_r[qi], mx);
        float fct = exp2f_fast(m_r[qi] - mn);
        m_r[qi] = mn;
        l_acc[qi] *= fct;
#pragma unroll
        for (int cb = 0; cb < 4; cb++)
#pragma unroll
          for (int r = 0; r < 4; r++) o_acc[qi][cb][r] *= fct;
      }

      // ---- P = exp2(S - m) packed to bf16 words, all in-lane ----
      uint32_t W[4][2];
      const float m = m_r[qi];
#pragma unroll
      for (int cb = 0; cb < 4; cb++) {
        float p0 = exp2f_fast(sc[qi][cb][0] - m);
        float p1 = exp2f_fast(sc[qi][cb][1] - m);
        float p2 = exp2f_fast(sc[qi][cb][2] - m);
        float p3 = exp2f_fast(sc[qi][cb][3] - m);
        W[cb][0] = cvt_pk_bf16(p0, p1);
        W[cb][1] = cvt_pk_bf16(p2, p3);
      }

      // ---- O^T += V^T P^T (k-dim permuted to match in-lane P words), l += 1.P ----
      __builtin_amdgcn_s_setprio(1);
#pragma unroll
      for (int ks = 0; ks < 2; ks++) {
        union { short8 v; uint32_t u[4]; } pb;
        pb.u[0] = W[2 * ks][0];
        pb.u[1] = W[2 * ks][1];
        pb.u[2] = W[2 * ks + 1][0];
        pb.u[3] = W[2 * ks + 1][1];
        l_acc[qi] = __builtin_amdgcn_mfma_f32_16x16x32_bf16(onesf, pb.v, l_acc[qi], 0, 0, 0);
#pragma unroll
        for (int cb = 0; cb < 4; cb++) {
          const ushort* vb = &vbuf[sel][(cb * 16 + l15) * 64];
          union { short8 v; uint2 d2[2]; } vv;
          vv.d2[0] = *(const uint2*)(vb + vo[ks][0]);
          vv.d2[1] = *(const uint2*)(vb + vo[ks][1]);
          o_acc[qi][cb] = __builtin_amdgcn_mfma_f32_16x16x32_bf16(vv.v, pb.v, o_acc[qi][cb], 0, 0, 0);
        }
      }
      __builtin_amdgcn_s_setprio(0);
    }
    __syncthreads();
  }

  // ---- epilogue: O^T / l -> o[B][S][H*64] (bf16, packed 8B stores) ----
#pragma unroll
  for (int qi = 0; qi < 2; qi++) {
    const float inv = 1.f / l_acc[qi][0];
    ushort* ob = o + ((size_t)b * S_ + q0 + w * 32 + qi * 16 + l15) * DM + h * HD + 4 * g;
#pragma unroll
    for (int cb = 0; cb < 4; cb++) {
      uint2 st;
      st.x = cvt_pk_bf16(o_acc[qi][cb][0] * inv, o_acc[qi][cb][1] * inv);
      st.y = cvt_pk_bf16(o_acc[qi][cb][2] * inv, o_acc[qi][cb][3] * inv);
      *(uint2*)(ob + cb * 16) = st;
    }
  }
}

// ---------------- launch ----------------
extern "C" void kernel_launch(void* const* d_in, const int* in_sizes, int n_in,
                              void* d_out, int out_size, void* d_ws, size_t ws_size,
                              hipStream_t stream) {
  const float* Q  = (const float*)d_in[0];
  const float* K  = (const float*)d_in[1];
  const float* V  = (const float*)d_in[2];
  const float* Wq = (const float*)d_in[3];
  const float* bq = (const float*)d_in[4];
  const float* Wk = (const float*)d_in[5];
  const float* bk = (const float*)d_in[6];
  const float* Wv = (const float*)d_in[7];
  const float* bv = (const float*)d_in[8];
  const float* Wo = (const float*)d_in[9];
  const float* bo = (const float*)d_in[10];
  float* out = (float*)d_out;
  ushort* ws = (ushort*)d_ws;

  const size_t WN = (size_t)1024 * 1024;       // weight elems
  const size_t PN = (size_t)B_ * S_ * DM;      // activation elems (8.39M)
  ushort* wqT = ws;
  ushort* wkT = ws + WN;
  ushort* wvT = ws + 2 * WN;
  ushort* woT = ws + 3 * WN;
  ushort* qws = ws + 4 * WN;
  ushort* kws = qws + PN;
  ushort* ows = kws + PN;
  ushort* vt  = (ushort*)d_out;  // V^T scratch in d_out (bf16 16.8MB < fp32 33.5MB); overwritten by final GEMM

  transposeW<<<256, 256, 0, stream>>>(Wq, wqT);
  transposeW<<<256, 256, 0, stream>>>(Wk, wkT);
  transposeW<<<256, 256, 0, stream>>>(Wv, wvT);
  transposeW<<<256, 256, 0, stream>>>(Wo, woT);

  dim3 gg(64, 8);  // M/128 x N/128
  // Q pre-scaled by (1/8)*log2(e): attention scores land in the log2 domain
  gemm_bt<1, 1><<<gg, 256, 0, stream>>>(Q, wqT, bq, qws, 8192, 1024, 1024, 0.18033688f);
  gemm_bt<1, 1><<<gg, 256, 0, stream>>>(K, wkT, bk, kws, 8192, 1024, 1024, 1.0f);
  gemm_bt<1, 2><<<gg, 256, 0, stream>>>(V, wvT, bv, vt, 8192, 1024, 1024, 1.0f);

  attn<<<BH * 16, 256, 0, stream>>>(qws, kws, vt, ows);

  gemm_bt<0, 0><<<gg, 256, 0, stream>>>(ows, woT, bo, out, 8192, 1024, 1024, 1.0f);
}

// Round 5
// 228.199 us; speedup vs baseline: 1.4758x; 1.0347x over previous
//
#include <hip/hip_runtime.h>
#include <hip/hip_bf16.h>
#include <stdint.h>

// MHA: B=4, S=2048, D_MODEL=1024, H=16, hd=64.
// Interface: fp32 in / fp32 out. Internal compute: bf16 MFMA.

#define B_  4
#define S_  2048
#define DM  1024
#define H_  16
#define HD  64
#define BH  (B_ * H_)

typedef __attribute__((ext_vector_type(8))) short short8;
typedef __attribute__((ext_vector_type(4))) float f32x4;

union U8 { short8 v; ushort u[8]; };

__device__ __forceinline__ ushort f2bf(float f) {
  union { float f; uint32_t i; } x; x.f = f;
  uint32_t r = (x.i + 0x7FFFu + ((x.i >> 16) & 1u)) >> 16;
  return (ushort)r;
}

// packed f32x2 -> bf16x2 (RNE), gfx950 hw convert; no builtin exists (m240)
__device__ __forceinline__ uint32_t cvt_pk_bf16(float a, float b) {
  uint32_t r;
  asm("v_cvt_pk_bf16_f32 %0, %1, %2" : "=v"(r) : "v"(a), "v"(b));
  return r;
}

// raw 2^x (v_exp_f32 IS exp2)
__device__ __forceinline__ float exp2f_fast(float x) {
  float r;
  asm("v_exp_f32 %0, %1" : "=v"(r) : "v"(x));
  return r;
}

__device__ __forceinline__ void glds16(const ushort* g, ushort* l) {
  __builtin_amdgcn_global_load_lds(
      (const __attribute__((address_space(1))) void*)g,
      (__attribute__((address_space(3))) void*)l, 16, 0, 0);
}

#define MAX3(a, b, c) fmaxf(fmaxf((a), (b)), (c))

// ---------------- weight ingest: fp32 [1024][1024] -> bf16 transposed (4 fused) ----------------
__global__ __launch_bounds__(256) void transposeW4(
    const float* __restrict__ s0, const float* __restrict__ s1,
    const float* __restrict__ s2, const float* __restrict__ s3,
    ushort* __restrict__ dbase) {
  __shared__ __align__(16) ushort tile[64][72];
  const int t = threadIdx.x;
  const int bx = blockIdx.x & 15;   // src col block
  const int by = blockIdx.x >> 4;   // src row block
  const int wsel = blockIdx.y;
  const float* src = wsel == 0 ? s0 : (wsel == 1 ? s1 : (wsel == 2 ? s2 : s3));
  ushort* dst = dbase + (size_t)wsel * 1024 * 1024;
#pragma unroll
  for (int i = 0; i < 2; i++) {
    int e = (i * 256 + t) * 8;
    int r = e >> 6, c = e & 63;
    const float* sp = src + (size_t)(by * 64 + r) * 1024 + bx * 64 + c;
    float4 a = ((const float4*)sp)[0];
    float4 b = ((const float4*)sp)[1];
    tile[r][c + 0] = f2bf(a.x); tile[r][c + 1] = f2bf(a.y);
    tile[r][c + 2] = f2bf(a.z); tile[r][c + 3] = f2bf(a.w);
    tile[r][c + 4] = f2bf(b.x); tile[r][c + 5] = f2bf(b.y);
    tile[r][c + 6] = f2bf(b.z); tile[r][c + 7] = f2bf(b.w);
  }
  __syncthreads();
#pragma unroll
  for (int i = 0; i < 2; i++) {
    int e = (i * 256 + t) * 8;
    int r = e >> 6, c = e & 63;
    U8 st;
#pragma unroll
    for (int j = 0; j < 8; j++) st.u[j] = tile[c + j][r];
    *(short8*)(dst + (size_t)(bx * 64 + r) * 1024 + by * 64 + c) = st.v;
  }
}

// ---------------- GEMM: C[M][N] = A[M][K] * BT[N][K]^T + bias ----------------
// AFP32: A is fp32 (reg-staged + cvt_pk), else bf16 via global_load_lds.
// CMODE 0: fp32 row-major out.
// CMODE 1: bf16 head-split [B][H][S][64] out.
// CMODE 2: bf16 V^T [BH][64][S] out with 8B-subchunk swizzle (phys = logical ^ (d&15))
//          baked per 64-col block -> attn stages vbuf with a LINEAR copy.
template<int AFP32, int CMODE>
__global__ __launch_bounds__(256, 2) void gemm_bt(
    const void* __restrict__ Ap, const ushort* __restrict__ BT,
    const float* __restrict__ bias, void* __restrict__ Cp,
    int M, int N, int K, float oscale) {
  __shared__ __align__(16) ushort lA[128 * 32];
  __shared__ __align__(16) ushort lB[128 * 32];
  const int t = threadIdx.x;
  const int lane = t & 63;
  const int w = t >> 6;
  const int wr = w >> 1, wc = w & 1;
  const int bm0 = blockIdx.x * 128;
  const int bn0 = blockIdx.y * 128;
  f32x4 acc[4][4] = {};

  const int arow = t >> 2;           // 0..63
  const int acol = (t & 3) * 8;      // element offset within 32-wide K slab
  const ushort* gA0 = (const ushort*)Ap + (size_t)(bm0 + arow) * K + acol;
  const ushort* gA1 = (const ushort*)Ap + (size_t)(bm0 + 64 + arow) * K + acol;
  const float*  fA0 = (const float*)Ap + (size_t)(bm0 + arow) * K + acol;
  const float*  fA1 = (const float*)Ap + (size_t)(bm0 + 64 + arow) * K + acol;
  const ushort* gB0 = BT + (size_t)(bn0 + arow) * K + acol;
  const ushort* gB1 = BT + (size_t)(bn0 + 64 + arow) * K + acol;

  for (int k0 = 0; k0 < K; k0 += 32) {
    if (k0) __syncthreads();
    if constexpr (AFP32) {
      float4 x0 = ((const float4*)(fA0 + k0))[0];
      float4 x1 = ((const float4*)(fA0 + k0))[1];
      float4 y0 = ((const float4*)(fA1 + k0))[0];
      float4 y1 = ((const float4*)(fA1 + k0))[1];
      union { short8 v; uint32_t u[4]; } s0, s1;
      s0.u[0] = cvt_pk_bf16(x0.x, x0.y); s0.u[1] = cvt_pk_bf16(x0.z, x0.w);
      s0.u[2] = cvt_pk_bf16(x1.x, x1.y); s0.u[3] = cvt_pk_bf16(x1.z, x1.w);
      s1.u[0] = cvt_pk_bf16(y0.x, y0.y); s1.u[1] = cvt_pk_bf16(y0.z, y0.w);
      s1.u[2] = cvt_pk_bf16(y1.x, y1.y); s1.u[3] = cvt_pk_bf16(y1.z, y1.w);
      *(short8*)&lA[t * 8] = s0.v;
      *(short8*)&lA[2048 + t * 8] = s1.v;
    } else {
      glds16(gA0 + k0, &lA[t * 8]);
      glds16(gA1 + k0, &lA[2048 + t * 8]);
    }
    glds16(gB0 + k0, &lB[t * 8]);
    glds16(gB1 + k0, &lB[2048 + t * 8]);
    __syncthreads();
    short8 af[4], bf[4];
#pragma unroll
    for (int i = 0; i < 4; i++)
      af[i] = *(const short8*)&lA[(wr * 64 + i * 16 + (lane & 15)) * 32 + (lane >> 4) * 8];
#pragma unroll
    for (int j = 0; j < 4; j++)
      bf[j] = *(const short8*)&lB[(wc * 64 + j * 16 + (lane & 15)) * 32 + (lane >> 4) * 8];
#pragma unroll
    for (int i = 0; i < 4; i++)
#pragma unroll
      for (int j = 0; j < 4; j++)
        acc[i][j] = __builtin_amdgcn_mfma_f32_16x16x32_bf16(af[i], bf[j], acc[i][j], 0, 0, 0);
  }

  const int r0 = (lane >> 4) * 4;
#pragma unroll
  for (int j = 0; j < 4; j++) {
    const int col = bn0 + wc * 64 + j * 16 + (lane & 15);
    const float bc = bias[col];
#pragma unroll
    for (int i = 0; i < 4; i++) {
      const int row = bm0 + wr * 64 + i * 16 + r0;   // row % 4 == 0
      if constexpr (CMODE == 2) {
        // V^T swizzled: 4 consecutive s = one 8B sub-chunk
        const int bb = row >> 11, s = row & 2047;
        const int hh = col >> 6, d = col & 63;
        uint32_t p01 = cvt_pk_bf16((acc[i][j][0] + bc) * oscale, (acc[i][j][1] + bc) * oscale);
        uint32_t p23 = cvt_pk_bf16((acc[i][j][2] + bc) * oscale, (acc[i][j][3] + bc) * oscale);
        ushort* vtb = (ushort*)Cp + (((size_t)bb * H_ + hh) * HD + d) * (size_t)S_;
        const int sc = (s & 63) >> 2;                // logical 8B sub-chunk in 64-col block
        *(uint2*)(vtb + (s & ~63) + ((sc ^ (d & 15)) << 2)) = (uint2){p01, p23};
      } else {
#pragma unroll
        for (int r = 0; r < 4; r++) {
          float val = (acc[i][j][r] + bc) * oscale;
          if constexpr (CMODE == 0) {
            ((float*)Cp)[(size_t)(row + r) * N + col] = val;
          } else {
            int rr = row + r;
            int b = rr >> 11, s = rr & 2047;
            int h = col >> 6, d = col & 63;
            ((ushort*)Cp)[(((size_t)b * H_ + h) * S_ + s) * HD + d] = f2bf(val);
          }
        }
      }
    }
  }
}

// ---------------- flash attention (swapped-QK^T, fully in-register P) ----------------
// q,k: bf16 [BH][S][64] (q pre-scaled by log2(e)/8), vt: bf16 [BH][64][S] 8B-swizzled,
// o: bf16 [B][S][1024]
// Block: 256 threads (4 waves), Q-tile 128 rows (32/wave). KV tile 64.
// Swapped QK^T: sc = mfma(K, Q) = S^T -> each lane owns ONE q-row (col = lane&15).
// OPTIMISTIC EXP: P = exp2(sc - m_old) issues right after QK; the tile max
//   (in-lane max3 tree + 2 shfl_xor, overlapped with the exp/cvt stream) only
//   gates the rare-recompute vote. Unstable case (first tile + <1% after)
//   rescales o/l and recomputes P with the new m -> numerics identical to R3.
// Cross-lane max uses __shfl_xor (VERIFIED R1-R3). NOTE: R4's 2-operand inline-asm
//   v_permlane16/32_swap_b32 rowmax was WRONG (m_r diverged across the 4 lanes of a
//   q-row -> 8.3e-2 absmax). Do not re-introduce without a verified builtin.
// P packs straight into PV fragment slots (pbq[qi][ks]) at cvt time, zero repack.
// LDS = 16K(kbuf)+16K(vbuf) = 32768 B.
__global__ __launch_bounds__(256, 4) void attn(
    const ushort* __restrict__ q, const ushort* __restrict__ k,
    const ushort* __restrict__ vt, ushort* __restrict__ o) {
  __shared__ __align__(16) ushort kbuf[2][4096];
  __shared__ __align__(16) ushort vbuf[2][4096];
  const int t = threadIdx.x;
  const int lane = t & 63;
  const int w = t >> 6;
  // XCD-bijective swizzle: 1024 blocks, 16 q-tiles/head -> one head's blocks share an XCD L2
  const int L = ((blockIdx.x & 7) << 7) + (blockIdx.x >> 3);
  const int bh = L >> 4;
  const int q0 = (L & 15) * 128;
  const int b = bh >> 4, h = bh & 15;
  const int l15 = lane & 15;
  const int g = lane >> 4;

  const ushort* kbase  = k  + (size_t)bh * S_ * HD;
  const ushort* vtbase = vt + (size_t)bh * HD * S_;

  // Q fragments: 32 rows per wave, hd=64 in two x-slabs (used as MFMA B operand)
  short8 qf[2][2];
#pragma unroll
  for (int qi = 0; qi < 2; qi++) {
    const ushort* qp = q + ((size_t)bh * S_ + q0 + w * 32 + qi * 16 + l15) * HD + g * 8;
    qf[qi][0] = *(const short8*)qp;
    qf[qi][1] = *(const short8*)(qp + 32);
  }

  // ones A-fragment for l accumulation (bf16 1.0 = 0x3F80)
  short8 onesf;
#pragma unroll
  for (int j = 0; j < 8; j++) onesf[j] = (short)0x3F80;

  float m_r[2] = {-1e30f, -1e30f};
  f32x4 l_acc[2];
  f32x4 o_acc[2][4];
#pragma unroll
  for (int qi = 0; qi < 2; qi++) {
    l_acc[qi] = (f32x4){0.f, 0.f, 0.f, 0.f};
#pragma unroll
    for (int cb = 0; cb < 4; cb++) o_acc[qi][cb] = (f32x4){0.f, 0.f, 0.f, 0.f};
  }

  // V-read sub-chunk offsets (ushort units), loop/cb-invariant: (8ks+g+{0,4}) ^ l15
  int vo[2][2];
#pragma unroll
  for (int ks = 0; ks < 2; ks++) {
    vo[ks][0] = ((8 * ks + g) ^ l15) << 2;
    vo[ks][1] = ((8 * ks + 4 + g) ^ l15) << 2;
  }

  // stage one 64-kv tile: K with XOR-swizzled source (16B chunks), V linear (pre-swizzled in vt)
  auto STAGE = [&](int sel_, int kv0) {
#pragma unroll
    for (int i = 0; i < 2; i++) {
      int c = i * 256 + t;            // 16B-chunk index, 512 chunks per tile
      int row = c >> 3;
      int cc = (c & 7) ^ (row & 7);   // pre-swizzled source chunk (K only)
      glds16(kbase + (size_t)(kv0 + row) * HD + cc * 8, &kbuf[sel_][c * 8]);
      glds16(vtbase + (size_t)row * S_ + kv0 + (c & 7) * 8, &vbuf[sel_][c * 8]);
    }
  };

  STAGE(0, 0);
  __syncthreads();

  int sel = 0;
  for (int kv0 = 0; kv0 < S_; kv0 += 64, sel ^= 1) {
    if (kv0 + 64 < S_) STAGE(sel ^ 1, kv0 + 64);

    // ---- S^T = K (Q*log2e/8)^T : lane holds k-rows (4g+r per cb) of q-col l15 ----
    f32x4 sc[2][4];
#pragma unroll
    for (int qi = 0; qi < 2; qi++)
#pragma unroll
      for (int cb = 0; cb < 4; cb++) sc[qi][cb] = (f32x4){0.f, 0.f, 0.f, 0.f};
    __builtin_amdgcn_s_setprio(1);
#pragma unroll
    for (int cb = 0; cb < 4; cb++) {
      const int row = cb * 16 + l15;
      const int r7 = row & 7;
      short8 kf0 = *(const short8*)&kbuf[sel][(row * 8 + (g ^ r7)) * 8];
      short8 kf1 = *(const short8*)&kbuf[sel][(row * 8 + ((4 + g) ^ r7)) * 8];
#pragma unroll
      for (int qi = 0; qi < 2; qi++) {
        sc[qi][cb] = __builtin_amdgcn_mfma_f32_16x16x32_bf16(kf0, qf[qi][0], sc[qi][cb], 0, 0, 0);
        sc[qi][cb] = __builtin_amdgcn_mfma_f32_16x16x32_bf16(kf1, qf[qi][1], sc[qi][cb], 0, 0, 0);
      }
    }
    __builtin_amdgcn_s_setprio(0);

    // ---- softmax, both qi (PV fragments pbq assemble directly) ----
    union PB { short8 v; uint32_t u[4]; } pbq[2][2];
#pragma unroll
    for (int qi = 0; qi < 2; qi++) {
      const float m = m_r[qi];
      // optimistic P with current m (independent of this tile's max)
#pragma unroll
      for (int cb = 0; cb < 4; cb++) {
        float p0 = exp2f_fast(sc[qi][cb][0] - m);
        float p1 = exp2f_fast(sc[qi][cb][1] - m);
        float p2 = exp2f_fast(sc[qi][cb][2] - m);
        float p3 = exp2f_fast(sc[qi][cb][3] - m);
        pbq[qi][cb >> 1].u[(cb & 1) * 2 + 0] = cvt_pk_bf16(p0, p1);
        pbq[qi][cb >> 1].u[(cb & 1) * 2 + 1] = cvt_pk_bf16(p2, p3);
      }
      // tile max in parallel (in-lane max3 tree + verified shfl_xor cross-lane)
      float z0 = MAX3(sc[qi][0][0], sc[qi][0][1], sc[qi][0][2]);
      float z1 = MAX3(sc[qi][0][3], sc[qi][1][0], sc[qi][1][1]);
      float z2 = MAX3(sc[qi][1][2], sc[qi][1][3], sc[qi][2][0]);
      float z3 = MAX3(sc[qi][2][1], sc[qi][2][2], sc[qi][2][3]);
      float z4 = MAX3(sc[qi][3][0], sc[qi][3][1], sc[qi][3][2]);
      float mx = MAX3(MAX3(z0, z1, z2), fmaxf(z3, z4), sc[qi][3][3]);
      mx = fmaxf(mx, __shfl_xor(mx, 16));
      mx = fmaxf(mx, __shfl_xor(mx, 32));

      // rare path: max grew past m + 8*log2e (always taken on first tile)
      const float THR = 11.5415603f;  // 8 * log2(e)
      if (!__all(mx <= m + THR)) {
        float mn = fmaxf(m, mx);
        float fct = exp2f_fast(m - mn);
        m_r[qi] = mn;
        l_acc[qi] *= fct;
#pragma unroll
        for (int cb = 0; cb < 4; cb++)
#pragma unroll
          for (int r = 0; r < 4; r++) o_acc[qi][cb][r] *= fct;
#pragma unroll
        for (int cb = 0; cb < 4; cb++) {
          float p0 = exp2f_fast(sc[qi][cb][0] - mn);
          float p1 = exp2f_fast(sc[qi][cb][1] - mn);
          float p2 = exp2f_fast(sc[qi][cb][2] - mn);
          float p3 = exp2f_fast(sc[qi][cb][3] - mn);
          pbq[qi][cb >> 1].u[(cb & 1) * 2 + 0] = cvt_pk_bf16(p0, p1);
          pbq[qi][cb >> 1].u[(cb & 1) * 2 + 1] = cvt_pk_bf16(p2, p3);
        }
      }
    }

    // ---- O^T += V^T P^T (k-dim permuted to match in-lane P words), l += 1.P ----
    __builtin_amdgcn_s_setprio(1);
#pragma unroll
    for (int qi = 0; qi < 2; qi++) {
#pragma unroll
      for (int ks = 0; ks < 2; ks++) {
        l_acc[qi] = __builtin_amdgcn_mfma_f32_16x16x32_bf16(onesf, pbq[qi][ks].v, l_acc[qi], 0, 0, 0);
#pragma unroll
        for (int cb = 0; cb < 4; cb++) {
          const ushort* vb = &vbuf[sel][(cb * 16 + l15) * 64];
          union { short8 v; uint2 d2[2]; } vv;
          vv.d2[0] = *(const uint2*)(vb + vo[ks][0]);
          vv.d2[1] = *(const uint2*)(vb + vo[ks][1]);
          o_acc[qi][cb] = __builtin_amdgcn_mfma_f32_16x16x32_bf16(vv.v, pbq[qi][ks].v, o_acc[qi][cb], 0, 0, 0);
        }
      }
    }
    __builtin_amdgcn_s_setprio(0);
    __syncthreads();
  }

  // ---- epilogue: O^T / l -> o[B][S][H*64] (bf16, packed 8B stores) ----
#pragma unroll
  for (int qi = 0; qi < 2; qi++) {
    const float inv = 1.f / l_acc[qi][0];
    ushort* ob = o + ((size_t)b * S_ + q0 + w * 32 + qi * 16 + l15) * DM + h * HD + 4 * g;
#pragma unroll
    for (int cb = 0; cb < 4; cb++) {
      uint2 st;
      st.x = cvt_pk_bf16(o_acc[qi][cb][0] * inv, o_acc[qi][cb][1] * inv);
      st.y = cvt_pk_bf16(o_acc[qi][cb][2] * inv, o_acc[qi][cb][3] * inv);
      *(uint2*)(ob + cb * 16) = st;
    }
  }
}

// ---------------- launch ----------------
extern "C" void kernel_launch(void* const* d_in, const int* in_sizes, int n_in,
                              void* d_out, int out_size, void* d_ws, size_t ws_size,
                              hipStream_t stream) {
  const float* Q  = (const float*)d_in[0];
  const float* K  = (const float*)d_in[1];
  const float* V  = (const float*)d_in[2];
  const float* Wq = (const float*)d_in[3];
  const float* bq = (const float*)d_in[4];
  const float* Wk = (const float*)d_in[5];
  const float* bk = (const float*)d_in[6];
  const float* Wv = (const float*)d_in[7];
  const float* bv = (const float*)d_in[8];
  const float* Wo = (const float*)d_in[9];
  const float* bo = (const float*)d_in[10];
  float* out = (float*)d_out;
  ushort* ws = (ushort*)d_ws;

  const size_t WN = (size_t)1024 * 1024;       // weight elems
  const size_t PN = (size_t)B_ * S_ * DM;      // activation elems (8.39M)
  ushort* wqT = ws;
  ushort* wkT = ws + WN;
  ushort* wvT = ws + 2 * WN;
  ushort* woT = ws + 3 * WN;
  ushort* qws = ws + 4 * WN;
  ushort* kws = qws + PN;
  ushort* ows = kws + PN;
  ushort* vt  = (ushort*)d_out;  // V^T scratch in d_out (bf16 16.8MB < fp32 33.5MB); overwritten by final GEMM

  transposeW4<<<dim3(256, 4), 256, 0, stream>>>(Wq, Wk, Wv, Wo, ws);

  dim3 gg(64, 8);  // M/128 x N/128
  // Q pre-scaled by (1/8)*log2(e): attention scores land in the log2 domain
  gemm_bt<1, 1><<<gg, 256, 0, stream>>>(Q, wqT, bq, qws, 8192, 1024, 1024, 0.18033688f);
  gemm_bt<1, 1><<<gg, 256, 0, stream>>>(K, wkT, bk, kws, 8192, 1024, 1024, 1.0f);
  gemm_bt<1, 2><<<gg, 256, 0, stream>>>(V, wvT, bv, vt, 8192, 1024, 1024, 1.0f);

  attn<<<BH * 16, 256, 0, stream>>>(qws, kws, vt, ows);

  gemm_bt<0, 0><<<gg, 256, 0, stream>>>(ows, woT, bo, out, 8192, 1024, 1024, 1.0f);
}

// Round 6
// 196.376 us; speedup vs baseline: 1.7149x; 1.1621x over previous
//
#include <hip/hip_runtime.h>
#include <hip/hip_bf16.h>
#include <stdint.h>

// MHA: B=4, S=2048, D_MODEL=1024, H=16, hd=64.
// Interface: fp32 in / fp32 out. Internal compute: bf16 MFMA.

#define B_  4
#define S_  2048
#define DM  1024
#define H_  16
#define HD  64
#define BH  (B_ * H_)

typedef __attribute__((ext_vector_type(8))) short short8;
typedef __attribute__((ext_vector_type(4))) float f32x4;

union U8 { short8 v; ushort u[8]; };

__device__ __forceinline__ ushort f2bf(float f) {
  union { float f; uint32_t i; } x; x.f = f;
  uint32_t r = (x.i + 0x7FFFu + ((x.i >> 16) & 1u)) >> 16;
  return (ushort)r;
}

// packed f32x2 -> bf16x2 (RNE), gfx950 hw convert; no builtin exists (m240)
__device__ __forceinline__ uint32_t cvt_pk_bf16(float a, float b) {
  uint32_t r;
  asm("v_cvt_pk_bf16_f32 %0, %1, %2" : "=v"(r) : "v"(a), "v"(b));
  return r;
}

// raw 2^x (v_exp_f32 IS exp2)
__device__ __forceinline__ float exp2f_fast(float x) {
  float r;
  asm("v_exp_f32 %0, %1" : "=v"(r) : "v"(x));
  return r;
}

__device__ __forceinline__ void glds16(const ushort* g, ushort* l) {
  __builtin_amdgcn_global_load_lds(
      (const __attribute__((address_space(1))) void*)g,
      (__attribute__((address_space(3))) void*)l, 16, 0, 0);
}

#define MAX3(a, b, c) fmaxf(fmaxf((a), (b)), (c))

// ---------------- weight ingest: fp32 [1024][1024] -> bf16 transposed (4 fused) ----------------
__global__ __launch_bounds__(256) void transposeW4(
    const float* __restrict__ s0, const float* __restrict__ s1,
    const float* __restrict__ s2, const float* __restrict__ s3,
    ushort* __restrict__ dbase) {
  __shared__ __align__(16) ushort tile[64][72];
  const int t = threadIdx.x;
  const int bx = blockIdx.x & 15;   // src col block
  const int by = blockIdx.x >> 4;   // src row block
  const int wsel = blockIdx.y;
  const float* src = wsel == 0 ? s0 : (wsel == 1 ? s1 : (wsel == 2 ? s2 : s3));
  ushort* dst = dbase + (size_t)wsel * 1024 * 1024;
#pragma unroll
  for (int i = 0; i < 2; i++) {
    int e = (i * 256 + t) * 8;
    int r = e >> 6, c = e & 63;
    const float* sp = src + (size_t)(by * 64 + r) * 1024 + bx * 64 + c;
    float4 a = ((const float4*)sp)[0];
    float4 b = ((const float4*)sp)[1];
    tile[r][c + 0] = f2bf(a.x); tile[r][c + 1] = f2bf(a.y);
    tile[r][c + 2] = f2bf(a.z); tile[r][c + 3] = f2bf(a.w);
    tile[r][c + 4] = f2bf(b.x); tile[r][c + 5] = f2bf(b.y);
    tile[r][c + 6] = f2bf(b.z); tile[r][c + 7] = f2bf(b.w);
  }
  __syncthreads();
#pragma unroll
  for (int i = 0; i < 2; i++) {
    int e = (i * 256 + t) * 8;
    int r = e >> 6, c = e & 63;
    U8 st;
#pragma unroll
    for (int j = 0; j < 8; j++) st.u[j] = tile[c + j][r];
    *(short8*)(dst + (size_t)(bx * 64 + r) * 1024 + by * 64 + c) = st.v;
  }
}

// ---------------- fused QKV projection GEMM (z = 0/1/2 -> Q/K/V) ----------------
// C = A[8192][1024] * WT[1024][1024]^T + bias. A fp32 reg-staged + cvt_pk.
// z=0: Q -> bf16 head-split [B][H][S][64], oscale = log2(e)/8
// z=1: K -> bf16 head-split [B][H][S][64]
// z=2: V -> bf16 V^T [BH][64][S] with 8B-subchunk swizzle (phys = logical ^ (d&15))
__global__ __launch_bounds__(256, 2) void gemm_qkv(
    const float* __restrict__ Qa, const float* __restrict__ Ka, const float* __restrict__ Va,
    const ushort* __restrict__ WT,
    const float* __restrict__ bq, const float* __restrict__ bk, const float* __restrict__ bv,
    ushort* __restrict__ qws, ushort* __restrict__ kws, ushort* __restrict__ vt) {
  __shared__ __align__(16) ushort lA[128 * 32];
  __shared__ __align__(16) ushort lB[128 * 32];
  const int z = blockIdx.z;
  const float* Ap = z == 0 ? Qa : (z == 1 ? Ka : Va);
  const ushort* BT = WT + (size_t)z * 1024 * 1024;
  const float* bias = z == 0 ? bq : (z == 1 ? bk : bv);
  const float oscale = z == 0 ? 0.18033688f : 1.0f;  // (1/8)*log2(e) on Q
  const int t = threadIdx.x;
  const int lane = t & 63;
  const int w = t >> 6;
  const int wr = w >> 1, wc = w & 1;
  const int bm0 = blockIdx.x * 128;
  const int bn0 = blockIdx.y * 128;
  f32x4 acc[4][4] = {};

  const int arow = t >> 2;
  const int acol = (t & 3) * 8;
  const float* fA0 = Ap + (size_t)(bm0 + arow) * 1024 + acol;
  const float* fA1 = Ap + (size_t)(bm0 + 64 + arow) * 1024 + acol;
  const ushort* gB0 = BT + (size_t)(bn0 + arow) * 1024 + acol;
  const ushort* gB1 = BT + (size_t)(bn0 + 64 + arow) * 1024 + acol;

  for (int k0 = 0; k0 < 1024; k0 += 32) {
    if (k0) __syncthreads();
    float4 x0 = ((const float4*)(fA0 + k0))[0];
    float4 x1 = ((const float4*)(fA0 + k0))[1];
    float4 y0 = ((const float4*)(fA1 + k0))[0];
    float4 y1 = ((const float4*)(fA1 + k0))[1];
    union { short8 v; uint32_t u[4]; } s0, s1;
    s0.u[0] = cvt_pk_bf16(x0.x, x0.y); s0.u[1] = cvt_pk_bf16(x0.z, x0.w);
    s0.u[2] = cvt_pk_bf16(x1.x, x1.y); s0.u[3] = cvt_pk_bf16(x1.z, x1.w);
    s1.u[0] = cvt_pk_bf16(y0.x, y0.y); s1.u[1] = cvt_pk_bf16(y0.z, y0.w);
    s1.u[2] = cvt_pk_bf16(y1.x, y1.y); s1.u[3] = cvt_pk_bf16(y1.z, y1.w);
    *(short8*)&lA[t * 8] = s0.v;
    *(short8*)&lA[2048 + t * 8] = s1.v;
    glds16(gB0 + k0, &lB[t * 8]);
    glds16(gB1 + k0, &lB[2048 + t * 8]);
    __syncthreads();
    short8 af[4], bf[4];
#pragma unroll
    for (int i = 0; i < 4; i++)
      af[i] = *(const short8*)&lA[(wr * 64 + i * 16 + (lane & 15)) * 32 + (lane >> 4) * 8];
#pragma unroll
    for (int j = 0; j < 4; j++)
      bf[j] = *(const short8*)&lB[(wc * 64 + j * 16 + (lane & 15)) * 32 + (lane >> 4) * 8];
#pragma unroll
    for (int i = 0; i < 4; i++)
#pragma unroll
      for (int j = 0; j < 4; j++)
        acc[i][j] = __builtin_amdgcn_mfma_f32_16x16x32_bf16(af[i], bf[j], acc[i][j], 0, 0, 0);
  }

  const int r0 = (lane >> 4) * 4;
#pragma unroll
  for (int j = 0; j < 4; j++) {
    const int col = bn0 + wc * 64 + j * 16 + (lane & 15);
    const float bc = bias[col];
#pragma unroll
    for (int i = 0; i < 4; i++) {
      const int row = bm0 + wr * 64 + i * 16 + r0;   // row % 4 == 0
      const int bb = row >> 11, s = row & 2047;
      const int hh = col >> 6, d = col & 63;
      if (z == 2) {
        // V^T swizzled: 4 consecutive s = one 8B sub-chunk
        uint32_t p01 = cvt_pk_bf16(acc[i][j][0] + bc, acc[i][j][1] + bc);
        uint32_t p23 = cvt_pk_bf16(acc[i][j][2] + bc, acc[i][j][3] + bc);
        ushort* vtb = vt + (((size_t)bb * H_ + hh) * HD + d) * (size_t)S_;
        const int sc = (s & 63) >> 2;
        *(uint2*)(vtb + (s & ~63) + ((sc ^ (d & 15)) << 2)) = (uint2){p01, p23};
      } else {
        ushort* dst = z == 0 ? qws : kws;
#pragma unroll
        for (int r = 0; r < 4; r++) {
          float val = (acc[i][j][r] + bc) * oscale;
          dst[(((size_t)bb * H_ + hh) * S_ + (s + r)) * HD + d] = f2bf(val);
        }
      }
    }
  }
}

// ---------------- output projection GEMM: fp32 C = A_bf16 * BT^T + bias ----------------
__global__ __launch_bounds__(256, 2) void gemm_out(
    const ushort* __restrict__ Ap, const ushort* __restrict__ BT,
    const float* __restrict__ bias, float* __restrict__ Cp) {
  __shared__ __align__(16) ushort lA[128 * 32];
  __shared__ __align__(16) ushort lB[128 * 32];
  const int t = threadIdx.x;
  const int lane = t & 63;
  const int w = t >> 6;
  const int wr = w >> 1, wc = w & 1;
  const int bm0 = blockIdx.x * 128;
  const int bn0 = blockIdx.y * 128;
  f32x4 acc[4][4] = {};

  const int arow = t >> 2;
  const int acol = (t & 3) * 8;
  const ushort* gA0 = Ap + (size_t)(bm0 + arow) * 1024 + acol;
  const ushort* gA1 = Ap + (size_t)(bm0 + 64 + arow) * 1024 + acol;
  const ushort* gB0 = BT + (size_t)(bn0 + arow) * 1024 + acol;
  const ushort* gB1 = BT + (size_t)(bn0 + 64 + arow) * 1024 + acol;

  for (int k0 = 0; k0 < 1024; k0 += 32) {
    if (k0) __syncthreads();
    glds16(gA0 + k0, &lA[t * 8]);
    glds16(gA1 + k0, &lA[2048 + t * 8]);
    glds16(gB0 + k0, &lB[t * 8]);
    glds16(gB1 + k0, &lB[2048 + t * 8]);
    __syncthreads();
    short8 af[4], bf[4];
#pragma unroll
    for (int i = 0; i < 4; i++)
      af[i] = *(const short8*)&lA[(wr * 64 + i * 16 + (lane & 15)) * 32 + (lane >> 4) * 8];
#pragma unroll
    for (int j = 0; j < 4; j++)
      bf[j] = *(const short8*)&lB[(wc * 64 + j * 16 + (lane & 15)) * 32 + (lane >> 4) * 8];
#pragma unroll
    for (int i = 0; i < 4; i++)
#pragma unroll
      for (int j = 0; j < 4; j++)
        acc[i][j] = __builtin_amdgcn_mfma_f32_16x16x32_bf16(af[i], bf[j], acc[i][j], 0, 0, 0);
  }

  const int r0 = (lane >> 4) * 4;
#pragma unroll
  for (int j = 0; j < 4; j++) {
    const int col = bn0 + wc * 64 + j * 16 + (lane & 15);
    const float bc = bias[col];
#pragma unroll
    for (int i = 0; i < 4; i++) {
      const int row = bm0 + wr * 64 + i * 16 + r0;
#pragma unroll
      for (int r = 0; r < 4; r++)
        Cp[(size_t)(row + r) * 1024 + col] = acc[i][j][r] + bc;
    }
  }
}

// ---------------- flash attention (swapped-QK^T, in-register P, 64 q-rows/wave) ----------------
// R5 post-mortem: kernel was LDS-read-BW bound (16 waves/CU x 16KB (K+V tiles) per
// tile-round = 256KB/CU @ ~120B/cy ~= the measured 2120cy wall). Fix: 64 q-rows per
// wave (qi=0..3), 256-row Q-tile, 512 blocks of 4 waves -> K/V LDS bytes amortize
// over 2x the q-rows (128KB/CU/round); VALU becomes the binding pipe.
// kf/vv fragments hoisted outside qi loops: each LDS byte read once, used 4x.
// VGPR ~220 peak -> 2 waves/SIMD (launch_bounds(256,2), cap 256). Watch for spill.
// q,k: bf16 [BH][S][64] (q pre-scaled by log2(e)/8), vt: bf16 [BH][64][S] 8B-swizzled,
// o: bf16 [B][S][1024]
__global__ __launch_bounds__(256, 2) void attn(
    const ushort* __restrict__ q, const ushort* __restrict__ k,
    const ushort* __restrict__ vt, ushort* __restrict__ o) {
  __shared__ __align__(16) ushort kbuf[2][4096];
  __shared__ __align__(16) ushort vbuf[2][4096];
  const int t = threadIdx.x;
  const int lane = t & 63;
  const int w = t >> 6;
  // XCD-bijective swizzle: 512 blocks, 8 q-tiles/head -> each XCD owns 8 whole heads
  const int L = ((blockIdx.x & 7) << 6) + (blockIdx.x >> 3);
  const int bh = L >> 3;
  const int q0 = (L & 7) * 256;
  const int b = bh >> 4, h = bh & 15;
  const int l15 = lane & 15;
  const int g = lane >> 4;

  const ushort* kbase  = k  + (size_t)bh * S_ * HD;
  const ushort* vtbase = vt + (size_t)bh * HD * S_;

  // Q fragments: 64 rows per wave (4 x 16), hd=64 in two x-slabs (MFMA B operand)
  short8 qf[4][2];
#pragma unroll
  for (int qi = 0; qi < 4; qi++) {
    const ushort* qp = q + ((size_t)bh * S_ + q0 + w * 64 + qi * 16 + l15) * HD + g * 8;
    qf[qi][0] = *(const short8*)qp;
    qf[qi][1] = *(const short8*)(qp + 32);
  }

  // ones A-fragment for l accumulation (bf16 1.0 = 0x3F80)
  short8 onesf;
#pragma unroll
  for (int j = 0; j < 8; j++) onesf[j] = (short)0x3F80;

  float m_r[4] = {-1e30f, -1e30f, -1e30f, -1e30f};
  f32x4 l_acc[4];
  f32x4 o_acc[4][4];
#pragma unroll
  for (int qi = 0; qi < 4; qi++) {
    l_acc[qi] = (f32x4){0.f, 0.f, 0.f, 0.f};
#pragma unroll
    for (int cb = 0; cb < 4; cb++) o_acc[qi][cb] = (f32x4){0.f, 0.f, 0.f, 0.f};
  }

  // V-read sub-chunk offsets (ushort units), loop/cb-invariant: (8ks+g+{0,4}) ^ l15
  int vo[2][2];
#pragma unroll
  for (int ks = 0; ks < 2; ks++) {
    vo[ks][0] = ((8 * ks + g) ^ l15) << 2;
    vo[ks][1] = ((8 * ks + 4 + g) ^ l15) << 2;
  }

  // stage one 64-kv tile: K with XOR-swizzled source (16B chunks), V linear (pre-swizzled in vt)
  auto STAGE = [&](int sel_, int kv0) {
#pragma unroll
    for (int i = 0; i < 2; i++) {
      int c = i * 256 + t;            // 16B-chunk index, 512 chunks per tile
      int row = c >> 3;
      int cc = (c & 7) ^ (row & 7);   // pre-swizzled source chunk (K only)
      glds16(kbase + (size_t)(kv0 + row) * HD + cc * 8, &kbuf[sel_][c * 8]);
      glds16(vtbase + (size_t)row * S_ + kv0 + (c & 7) * 8, &vbuf[sel_][c * 8]);
    }
  };

  STAGE(0, 0);
  __syncthreads();

  int sel = 0;
  for (int kv0 = 0; kv0 < S_; kv0 += 64, sel ^= 1) {
    if (kv0 + 64 < S_) STAGE(sel ^ 1, kv0 + 64);

    // ---- S^T = K (Q*log2e/8)^T : lane holds k-rows (4g+r per cb) of q-col l15 ----
    f32x4 sc[4][4];
#pragma unroll
    for (int qi = 0; qi < 4; qi++)
#pragma unroll
      for (int cb = 0; cb < 4; cb++) sc[qi][cb] = (f32x4){0.f, 0.f, 0.f, 0.f};
    __builtin_amdgcn_s_setprio(1);
#pragma unroll
    for (int cb = 0; cb < 4; cb++) {
      const int row = cb * 16 + l15;
      const int r7 = row & 7;
      short8 kf0 = *(const short8*)&kbuf[sel][(row * 8 + (g ^ r7)) * 8];
      short8 kf1 = *(const short8*)&kbuf[sel][(row * 8 + ((4 + g) ^ r7)) * 8];
#pragma unroll
      for (int qi = 0; qi < 4; qi++) {
        sc[qi][cb] = __builtin_amdgcn_mfma_f32_16x16x32_bf16(kf0, qf[qi][0], sc[qi][cb], 0, 0, 0);
        sc[qi][cb] = __builtin_amdgcn_mfma_f32_16x16x32_bf16(kf1, qf[qi][1], sc[qi][cb], 0, 0, 0);
      }
    }
    __builtin_amdgcn_s_setprio(0);

    // ---- softmax per qi (optimistic exp; shfl max off critical path) ----
    union PB { short8 v; uint32_t u[4]; } pbq[4][2];
#pragma unroll
    for (int qi = 0; qi < 4; qi++) {
      const float m = m_r[qi];
#pragma unroll
      for (int cb = 0; cb < 4; cb++) {
        float p0 = exp2f_fast(sc[qi][cb][0] - m);
        float p1 = exp2f_fast(sc[qi][cb][1] - m);
        float p2 = exp2f_fast(sc[qi][cb][2] - m);
        float p3 = exp2f_fast(sc[qi][cb][3] - m);
        pbq[qi][cb >> 1].u[(cb & 1) * 2 + 0] = cvt_pk_bf16(p0, p1);
        pbq[qi][cb >> 1].u[(cb & 1) * 2 + 1] = cvt_pk_bf16(p2, p3);
      }
      // tile max (in-lane max3 tree + verified shfl_xor cross-lane)
      float z0 = MAX3(sc[qi][0][0], sc[qi][0][1], sc[qi][0][2]);
      float z1 = MAX3(sc[qi][0][3], sc[qi][1][0], sc[qi][1][1]);
      float z2 = MAX3(sc[qi][1][2], sc[qi][1][3], sc[qi][2][0]);
      float z3 = MAX3(sc[qi][2][1], sc[qi][2][2], sc[qi][2][3]);
      float z4 = MAX3(sc[qi][3][0], sc[qi][3][1], sc[qi][3][2]);
      float mx = MAX3(MAX3(z0, z1, z2), fmaxf(z3, z4), sc[qi][3][3]);
      mx = fmaxf(mx, __shfl_xor(mx, 16));
      mx = fmaxf(mx, __shfl_xor(mx, 32));

      // rare path: max grew past m + 8*log2e (always taken on first tile)
      const float THR = 11.5415603f;  // 8 * log2(e)
      if (!__all(mx <= m + THR)) {
        float mn = fmaxf(m, mx);
        float fct = exp2f_fast(m - mn);
        m_r[qi] = mn;
        l_acc[qi] *= fct;
#pragma unroll
        for (int cb = 0; cb < 4; cb++)
#pragma unroll
          for (int r = 0; r < 4; r++) o_acc[qi][cb][r] *= fct;
#pragma unroll
        for (int cb = 0; cb < 4; cb++) {
          float p0 = exp2f_fast(sc[qi][cb][0] - mn);
          float p1 = exp2f_fast(sc[qi][cb][1] - mn);
          float p2 = exp2f_fast(sc[qi][cb][2] - mn);
          float p3 = exp2f_fast(sc[qi][cb][3] - mn);
          pbq[qi][cb >> 1].u[(cb & 1) * 2 + 0] = cvt_pk_bf16(p0, p1);
          pbq[qi][cb >> 1].u[(cb & 1) * 2 + 1] = cvt_pk_bf16(p2, p3);
        }
      }
    }

    // ---- O^T += V^T P^T, l += 1.P ; vv loaded once per (ks,cb), reused by 4 qi ----
    __builtin_amdgcn_s_setprio(1);
#pragma unroll
    for (int ks = 0; ks < 2; ks++) {
#pragma unroll
      for (int qi = 0; qi < 4; qi++)
        l_acc[qi] = __builtin_amdgcn_mfma_f32_16x16x32_bf16(onesf, pbq[qi][ks].v, l_acc[qi], 0, 0, 0);
#pragma unroll
      for (int cb = 0; cb < 4; cb++) {
        const ushort* vb = &vbuf[sel][(cb * 16 + l15) * 64];
        union { short8 v; uint2 d2[2]; } vv;
        vv.d2[0] = *(const uint2*)(vb + vo[ks][0]);
        vv.d2[1] = *(const uint2*)(vb + vo[ks][1]);
#pragma unroll
        for (int qi = 0; qi < 4; qi++)
          o_acc[qi][cb] = __builtin_amdgcn_mfma_f32_16x16x32_bf16(vv.v, pbq[qi][ks].v, o_acc[qi][cb], 0, 0, 0);
      }
    }
    __builtin_amdgcn_s_setprio(0);
    __syncthreads();
  }

  // ---- epilogue: O^T / l -> o[B][S][H*64] (bf16, packed 8B stores) ----
#pragma unroll
  for (int qi = 0; qi < 4; qi++) {
    const float inv = 1.f / l_acc[qi][0];
    ushort* ob = o + ((size_t)b * S_ + q0 + w * 64 + qi * 16 + l15) * DM + h * HD + 4 * g;
#pragma unroll
    for (int cb = 0; cb < 4; cb++) {
      uint2 st;
      st.x = cvt_pk_bf16(o_acc[qi][cb][0] * inv, o_acc[qi][cb][1] * inv);
      st.y = cvt_pk_bf16(o_acc[qi][cb][2] * inv, o_acc[qi][cb][3] * inv);
      *(uint2*)(ob + cb * 16) = st;
    }
  }
}

// ---------------- launch ----------------
extern "C" void kernel_launch(void* const* d_in, const int* in_sizes, int n_in,
                              void* d_out, int out_size, void* d_ws, size_t ws_size,
                              hipStream_t stream) {
  const float* Q  = (const float*)d_in[0];
  const float* K  = (const float*)d_in[1];
  const float* V  = (const float*)d_in[2];
  const float* Wq = (const float*)d_in[3];
  const float* bq = (const float*)d_in[4];
  const float* Wk = (const float*)d_in[5];
  const float* bk = (const float*)d_in[6];
  const float* Wv = (const float*)d_in[7];
  const float* bv = (const float*)d_in[8];
  const float* Wo = (const float*)d_in[9];
  const float* bo = (const float*)d_in[10];
  float* out = (float*)d_out;
  ushort* ws = (ushort*)d_ws;

  const size_t WN = (size_t)1024 * 1024;       // weight elems
  const size_t PN = (size_t)B_ * S_ * DM;      // activation elems (8.39M)
  ushort* wT  = ws;                             // wq/wk/wv/wo transposed, contiguous
  ushort* woT = ws + 3 * WN;
  ushort* qws = ws + 4 * WN;
  ushort* kws = qws + PN;
  ushort* ows = kws + PN;
  ushort* vt  = (ushort*)d_out;  // V^T scratch in d_out (bf16 16.8MB < fp32 33.5MB); overwritten by final GEMM

  transposeW4<<<dim3(256, 4), 256, 0, stream>>>(Wq, Wk, Wv, Wo, wT);

  // fused Q/K/V projections: grid.z selects input/bias/output/epilogue
  gemm_qkv<<<dim3(64, 8, 3), 256, 0, stream>>>(Q, K, V, wT, bq, bk, bv, qws, kws, vt);

  attn<<<BH * 8, 256, 0, stream>>>(qws, kws, vt, ows);

  gemm_out<<<dim3(64, 8), 256, 0, stream>>>(ows, woT, bo, out);
}